// Round 7
// baseline (509.028 us; speedup 1.0000x reference)
//
#include <hip/hip_runtime.h>
#include <hip/hip_bf16.h>
#include <stdint.h>

// Problem constants
#define B_    2
#define S_    4096
#define H_    1024
#define NKH_  8
#define NVH_  16
#define DK_   64
#define DV_   64
#define KEYD_ 512          // NKH*DK
#define CDIM_ 2048         // 2*KEYD + VAL_DIM
#define VALD_ 1024         // NVH*DV
#define NCHUNK_ 64         // S_/64
#define CS_   64           // chunk size

using bf16 = __hip_bfloat16;
using bf16x8 = __attribute__((ext_vector_type(8))) short;  // 8 bf16 = 4 VGPRs
using f32x4  = __attribute__((ext_vector_type(4))) float;

__device__ inline float bsh2f(short s) {
  union { ushort u; bf16 h; } c; c.u = (ushort)s; return __bfloat162float(c.h);
}
__device__ inline short f2bsh(float f) {
  union { ushort u; bf16 h; } c; c.h = __float2bfloat16(f); return (short)c.u;
}

// async global->LDS, 16B per lane; dest = uniform base + lane*16 (HW rule).
__device__ __forceinline__ void gload16(const bf16* g, short* lds) {
  __builtin_amdgcn_global_load_lds(
      (const __attribute__((address_space(1))) void*)g,
      (__attribute__((address_space(3))) void*)lds, 16, 0, 0);
}

// ---------------------------------------------------------------------------
// fp32 -> bf16 cast, 4 elems/thread (n % 4 == 0). (r2-validated structure)
// ---------------------------------------------------------------------------
__global__ __launch_bounds__(256) void castf2b(const float* __restrict__ x,
                                               bf16* __restrict__ y, long n) {
  const long i = ((long)blockIdx.x * 256 + threadIdx.x) * 4;
  if (i >= n) return;
  float4 v = *(const float4*)(x + i);
  union { ushort4 u; bf16 h[4]; } o;
  o.h[0] = __float2bfloat16(v.x);
  o.h[1] = __float2bfloat16(v.y);
  o.h[2] = __float2bfloat16(v.z);
  o.h[3] = __float2bfloat16(v.w);
  *(ushort4*)(y + i) = o.u;
}

// ---------------------------------------------------------------------------
// MFMA GEMM (r4-validated): C[m,n] = sum_k A[m,k]*B[n,k]; A,B bf16;
// C bf16 or fp32. 128x128 tile, 4 waves 2x2, 4x4 of 16x16x32 MFMA, BK=32.
// Staging via global_load_lds width=16 (m97 ladder step-3).
// ---------------------------------------------------------------------------
template <typename OT>
__global__ __launch_bounds__(256) void gemm_bt(const bf16* __restrict__ A,
                                               const bf16* __restrict__ Bm,
                                               OT* __restrict__ C,
                                               int M, int N, int K) {
  __shared__ short Asm[128 * 32];
  __shared__ short Bsm[128 * 32];
  const int t = threadIdx.x;
  const int w = t >> 6, l = t & 63;
  const int ntn = N >> 7;
  const int bm = blockIdx.x / ntn, bn = blockIdx.x % ntn;
  const int m0 = bm << 7, n0 = bn << 7;
  const int wm = (w >> 1) << 6, wn = (w & 1) << 6;

  f32x4 acc[4][4] = {};

  const int grow = l >> 2;            // 0..15 within slab
  const int gc8 = (l & 3) << 3;       // 0,8,16,24
  const bf16* Agl = A + (long)m0 * K + gc8;
  const bf16* Bgl = Bm + (long)n0 * K + gc8;

  const int lm = l & 15;
  const int kk = (l >> 4) << 3;
  const short* ar0 = &Asm[(wm + lm) * 32 + kk];
  const short* br0 = &Bsm[(wn + lm) * 32 + kk];

  for (int k0 = 0; k0 < K; k0 += 32) {
    __syncthreads();   // prev-iter LDS reads done
#pragma unroll
    for (int j = 0; j < 2; ++j) {
      const int s = w * 2 + j;        // slab 0..7 (wave-uniform)
      gload16(Agl + (long)(s * 16 + grow) * K + k0, &Asm[s * 16 * 32]);
      gload16(Bgl + (long)(s * 16 + grow) * K + k0, &Bsm[s * 16 * 32]);
    }
    __syncthreads();   // compiler drains vmcnt before barrier -> LDS ready
    bf16x8 af[4], bfr[4];
#pragma unroll
    for (int mi = 0; mi < 4; ++mi) af[mi] = *(const bf16x8*)(ar0 + mi * 16 * 32);
#pragma unroll
    for (int ni = 0; ni < 4; ++ni) bfr[ni] = *(const bf16x8*)(br0 + ni * 16 * 32);
#pragma unroll
    for (int mi = 0; mi < 4; ++mi)
#pragma unroll
      for (int ni = 0; ni < 4; ++ni)
        acc[mi][ni] = __builtin_amdgcn_mfma_f32_16x16x32_bf16(af[mi], bfr[ni],
                                                              acc[mi][ni], 0, 0, 0);
  }

  // C/D layout: col = l&15, row = (l>>4)*4 + reg
  const int r0 = (l >> 4) << 2;
  const int cn = l & 15;
#pragma unroll
  for (int mi = 0; mi < 4; ++mi)
#pragma unroll
    for (int ni = 0; ni < 4; ++ni) {
      long base = (long)(m0 + wm + mi * 16 + r0) * N + (n0 + wn + ni * 16 + cn);
#pragma unroll
      for (int r = 0; r < 4; ++r) {
        if constexpr (sizeof(OT) == 2)
          C[base + (long)r * N] = __float2bfloat16(acc[mi][ni][r]);
        else
          C[base + (long)r * N] = acc[mi][ni][r];
      }
    }
}

// ---------------------------------------------------------------------------
// conv3 (r5-validated): causal depthwise k=4 conv + silu + q-scale, 8 ch/thr.
// ---------------------------------------------------------------------------
__global__ __launch_bounds__(256) void conv3(const bf16* __restrict__ mixed,
                                             const float* __restrict__ cw,
                                             bf16* __restrict__ qkv) {
  const long idx = (long)blockIdx.x * 256 + threadIdx.x;  // over M*256 groups
  const int c0 = (int)(idx & 255) << 3;                   // channel group base
  const long row = idx >> 8;
  const int s = (int)(row & (S_ - 1));

  bf16x8 mv[4];
#pragma unroll
  for (int j = 0; j < 4; ++j) {
    if (s - 3 + j >= 0)
      mv[j] = *(const bf16x8*)(mixed + (row + j - 3) * CDIM_ + c0);
    else
      mv[j] = (bf16x8){0, 0, 0, 0, 0, 0, 0, 0};
  }

  const float qs = (c0 < KEYD_) ? 0.125f : 1.f;
  union { ushort4 u4[2]; short h[8]; } o;
#pragma unroll
  for (int e = 0; e < 8; ++e) {
    const float4 w = *(const float4*)(cw + (c0 + e) * 4);
    float acc = 0.f;
    acc = fmaf(w.x, bsh2f(mv[0][e]), acc);
    acc = fmaf(w.y, bsh2f(mv[1][e]), acc);
    acc = fmaf(w.z, bsh2f(mv[2][e]), acc);
    acc = fmaf(w.w, bsh2f(mv[3][e]), acc);
    const float y = qs * (acc / (1.f + __expf(-acc)));    // silu (+ q-scale)
    o.h[e] = f2bsh(y);
  }
  *(bf16x8*)((uint16_t*)qkv + row * CDIM_ + c0) = *(bf16x8*)&o.h[0];
}

// ---------------------------------------------------------------------------
// proj_ba2 (r3-validated): 8 rows per block; W traffic cut 8x.
// ---------------------------------------------------------------------------
__global__ __launch_bounds__(256) void proj_ba2(const float* __restrict__ hs,
                                                const float* __restrict__ Wb,
                                                const float* __restrict__ Wa,
                                                const float* __restrict__ dtb,
                                                const float* __restrict__ Alog,
                                                float* __restrict__ beta,
                                                float* __restrict__ g) {
  __shared__ float4 hrow[8][257];   // +1 float4 pad
  const long row0 = (long)blockIdx.x * 8;
  const int tid = threadIdx.x;
  for (int i = tid; i < 2048; i += 256) {
    const int r = i >> 8, c4 = i & 255;
    hrow[r][c4] = *(const float4*)(hs + (row0 + r) * H_ + (long)c4 * 4);
  }
  __syncthreads();
  const int j = tid >> 3, r = tid & 7;
  const float4* Wp = (const float4*)(j < 16 ? Wb + (long)j * H_
                                            : Wa + (long)(j - 16) * H_);
  float4 a4 = {0.f, 0.f, 0.f, 0.f};
#pragma unroll 4
  for (int i = 0; i < 256; ++i) {
    const float4 w = Wp[i];
    const float4 hv = hrow[r][i];
    a4.x = fmaf(w.x, hv.x, a4.x);
    a4.y = fmaf(w.y, hv.y, a4.y);
    a4.z = fmaf(w.z, hv.z, a4.z);
    a4.w = fmaf(w.w, hv.w, a4.w);
  }
  const float acc = (a4.x + a4.y) + (a4.z + a4.w);
  const long row = row0 + r;
  if (j < 16) {
    beta[row * NVH_ + j] = 1.f / (1.f + __expf(-acc));
  } else {
    const int hh = j - 16;
    const float x = acc + dtb[hh];
    const float sp = (x > 20.f) ? x : log1pf(__expf(x));
    g[row * NVH_ + hh] = -__expf(Alog[hh]) * sp;
  }
}

// ---------------------------------------------------------------------------
// chunk_pre (r7): per (b,h,chunk) task:
//   lg = cumsum(g); T[t,i] = beta_t e^{lg_t-lg_i}(k_t.k_i), i<t
//   solve (I+T)X = [diag(beta e^lg)K | diag(beta)V] -> W,U0
//   K' = e^{lg63-lg_t} k; McT = -K'^T W; Bc = U0^T K' (MFMA)
// r7: REGISTER-RESIDENT solve. x[64] in VGPRs (fully static indexing), tail
// updates read T as uniform float4 broadcasts only — no Xl LDS array (-34KB).
// Cross-update (rank-32 MFMA) result routed via bf16 Ucr aliasing dead Ksm.
// LDS 79.4KB -> 44.8KB => 3 WG/CU (launch_bounds (256,3) caps VGPR at 170).
// ---------------------------------------------------------------------------
__global__ __launch_bounds__(256, 3) void chunk_pre(const bf16* __restrict__ qkv,
                                                    const float* __restrict__ beta,
                                                    const float* __restrict__ g,
                                                    bf16* __restrict__ Wws,
                                                    bf16* __restrict__ U0ws,
                                                    float* __restrict__ lgws,
                                                    bf16* __restrict__ McT,
                                                    bf16* __restrict__ Bc) {
  __shared__ short Ksm[64][72];   // aliased: TloB (ph5), Ucr (ph6-7)
  __shared__ short Vsm[64][72];   // aliased: XB (ph4b-5), U0T (ph9-10)
  __shared__ float Tsm[64][64];   // aliased: WT (ph9-10)
  __shared__ short KpT[64][72];   // K'^T rows [k][t]
  __shared__ float lgs[64];
  __shared__ float bts[64];
  __shared__ float belg[64];

  // aliases (live ranges disjoint; barriers separate read/write phases)
  short (*XB)[36]   = (short (*)[36]) & Vsm[0][0];   // bf16 Xu [col][u], 9216B
  short (*TloB)[40] = (short (*)[40]) & Ksm[0][0];   // bf16 T[32+m][u], 2560B
  short (*UcrB)[68] = (short (*)[68]) & Ksm[0][0];   // bf16 cross-upd [row][col], 4352B
  short (*WT)[72]   = (short (*)[72]) & Tsm[0][0];
  short (*U0T)[72]  = Vsm;

  const int blk = blockIdx.x;
  const int hb = blk & 31, c = blk >> 5;   // hb fast: qkv-row L2 reuse
  const long task = (long)hb * 64 + c;
  const int h = hb & 15, b = hb >> 4, kh = h >> 1;
  const long t0 = (long)b * S_ + (long)c * CS_;
  const int tid = threadIdx.x;
  const int wv = tid >> 6, l = tid & 63;
  const int lm = l & 15, lk8 = (l >> 4) << 3;
  const int r0 = (l >> 4) << 2, cn = l & 15;
  const int srow = tid >> 2, scol = (tid & 3) * 16;

  // ph1: stage K,V
  {
    const bf16* kp = qkv + (t0 + srow) * CDIM_ + KEYD_ + kh * 64 + scol;
    const bf16* vp = qkv + (t0 + srow) * CDIM_ + 2 * KEYD_ + h * 64 + scol;
    *(bf16x8*)&Ksm[srow][scol]     = *(const bf16x8*)(kp);
    *(bf16x8*)&Ksm[srow][scol + 8] = *(const bf16x8*)(kp + 8);
    *(bf16x8*)&Vsm[srow][scol]     = *(const bf16x8*)(vp);
    *(bf16x8*)&Vsm[srow][scol + 8] = *(const bf16x8*)(vp + 8);
  }
  if (tid < 64) {
    bts[tid] = beta[(t0 + tid) * NVH_ + h];
    lgs[tid] = g[(t0 + tid) * NVH_ + h];
  }
  __syncthreads();

  // ph2: wave-parallel inclusive prefix sum of g (wave 0)
  if (tid < 64) {
    float x = lgs[tid];
#pragma unroll
    for (int d = 1; d < 64; d <<= 1) {
      const float y = __shfl_up(x, d);
      if (tid >= d) x += y;
    }
    lgs[tid] = x;
    belg[tid] = bts[tid] * __expf(x);
  }
  __syncthreads();

  // ph3: waves 0-1 KK^T -> T; waves 2-3 K'^T build
  if (tid < 128) {
    f32x4 acc[2][4] = {};
#pragma unroll
    for (int ks = 0; ks < 2; ++ks) {
      bf16x8 bfr[4];
#pragma unroll
      for (int ni = 0; ni < 4; ++ni)
        bfr[ni] = *(const bf16x8*)&Ksm[ni * 16 + lm][lk8 + ks * 32];
#pragma unroll
      for (int mi = 0; mi < 2; ++mi) {
        bf16x8 afr = *(const bf16x8*)&Ksm[(wv * 2 + mi) * 16 + lm][lk8 + ks * 32];
#pragma unroll
        for (int ni = 0; ni < 4; ++ni)
          acc[mi][ni] = __builtin_amdgcn_mfma_f32_16x16x32_bf16(afr, bfr[ni],
                                                                acc[mi][ni], 0, 0, 0);
      }
    }
#pragma unroll
    for (int mi = 0; mi < 2; ++mi)
#pragma unroll
      for (int ni = 0; ni < 4; ++ni)
#pragma unroll
        for (int r = 0; r < 4; ++r) {
          const int t = (wv * 2 + mi) * 16 + r0 + r;
          const int i = ni * 16 + cn;
          Tsm[t][i] = (i < t) ? bts[t] * __expf(lgs[t] - lgs[i]) * acc[mi][ni][r]
                              : 0.f;
        }
  } else {
    const int idx = tid - 128;
    const int tt = idx >> 1;
    const int o2 = (idx & 1) * 32;
    const float dec = __expf(lgs[63] - lgs[tt]);
#pragma unroll 8
    for (int k = 0; k < 32; ++k)
      KpT[o2 + k][tt] = f2bsh(dec * bsh2f(Ksm[tt][o2 + k]));
  }
  __syncthreads();   // Tsm, KpT, belg ready

  // register-resident solution column (threads 0-127)
  float x[64];
  const int colW = tid & 63;
  const bool isW = tid < 64;

  // 32x32 fp32 forward-sub on rows [base, base+32); x fully static-indexed.
  auto solve32 = [&](const int base) {
#pragma unroll
    for (int jj = 0; jj < 32; jj += 8) {
      const int j = base + jj;
      float xs[8];
#pragma unroll
      for (int a = 0; a < 8; ++a) xs[a] = x[j + a];
#pragma unroll
      for (int a = 1; a < 8; ++a)
#pragma unroll
        for (int bb = 0; bb < a; ++bb)
          xs[a] = fmaf(-Tsm[j + a][j + bb], xs[bb], xs[a]);
#pragma unroll
      for (int a = 1; a < 8; ++a) x[j + a] = xs[a];
#pragma unroll
      for (int t2 = jj + 8; t2 < 32; ++t2) {
        const int tt = base + t2;
        const float4 ta = *(const float4*)&Tsm[tt][j];
        const float4 tb = *(const float4*)&Tsm[tt][j + 4];
        float v = x[tt];
        v = fmaf(-ta.x, xs[0], v); v = fmaf(-ta.y, xs[1], v);
        v = fmaf(-ta.z, xs[2], v); v = fmaf(-ta.w, xs[3], v);
        v = fmaf(-tb.x, xs[4], v); v = fmaf(-tb.y, xs[5], v);
        v = fmaf(-tb.z, xs[6], v); v = fmaf(-tb.w, xs[7], v);
        x[tt] = v;
      }
    }
  };

  // ph4a: rhs init + upper 32x32 solve (threads 0-127; waves 2-3 idle,
  // co-resident WGs fill the SIMDs at 3 WG/CU)
  if (tid < 128) {
#pragma unroll
    for (int t = 0; t < CS_; ++t)
      x[t] = isW ? belg[t] * bsh2f(Ksm[t][colW])
                 : bts[t] * bsh2f(Vsm[t][colW]);
    solve32(0);
  }
  if (tid < 64) lgws[task * 64 + tid] = lgs[tid];
  __syncthreads();   // Ksm/Vsm reads done -> TloB/XB regions writable

  // ph4b: bf16 conversions (owners write XB; waves 2-3 write TloB)
  if (tid < 128) {
#pragma unroll
    for (int p = 0; p < 16; ++p) {
      short2 pk; pk.x = f2bsh(x[2 * p]); pk.y = f2bsh(x[2 * p + 1]);
      *(short2*)&XB[tid][2 * p] = pk;
    }
  } else {
    const int m = (tid - 128) >> 2, u0 = (tid & 3) * 8;
#pragma unroll
    for (int u = 0; u < 8; ++u)
      TloB[m][u0 + u] = f2bsh(Tsm[32 + m][u0 + u]);
  }
  __syncthreads();

  // ph5: rank-32 cross-update via MFMA (all 4 waves, 16 MFMAs)
  f32x4 uacc2[2][2] = {};
  {
#pragma unroll
    for (int ni2 = 0; ni2 < 2; ++ni2) {
      const int ni = wv * 2 + ni2;
      bf16x8 bfr = *(const bf16x8*)&XB[ni * 16 + lm][lk8];
#pragma unroll
      for (int mi = 0; mi < 2; ++mi) {
        bf16x8 afr = *(const bf16x8*)&TloB[mi * 16 + lm][lk8];
        uacc2[ni2][mi] = __builtin_amdgcn_mfma_f32_16x16x32_bf16(afr, bfr,
                                                                 uacc2[ni2][mi], 0, 0, 0);
      }
    }
  }
  __syncthreads();   // TloB reads done -> Ucr (same region) writable

  // ph6: scatter cross-update to owners (bf16)
#pragma unroll
  for (int ni2 = 0; ni2 < 2; ++ni2)
#pragma unroll
    for (int mi = 0; mi < 2; ++mi)
#pragma unroll
      for (int r = 0; r < 4; ++r)
        UcrB[mi * 16 + r0 + r][wv * 32 + ni2 * 16 + cn] = f2bsh(uacc2[ni2][mi][r]);
  __syncthreads();

  // ph7: subtract + lower 32x32 solve (threads 0-127)
  if (tid < 128) {
#pragma unroll
    for (int i = 0; i < 32; ++i)
      x[32 + i] -= bsh2f(UcrB[i][tid]);
    solve32(32);
  }
  __syncthreads();   // Tsm reads done -> WT region writable

  // ph9: write W/U0 to global + transposed bf16 into LDS (from registers)
  if (tid < 128) {
    bf16* dst = (isW ? Wws : U0ws) + task * 4096 + colW;
    short (*XT)[72] = isW ? WT : U0T;
#pragma unroll 4
    for (int t = 0; t < CS_; t += 2) {
      dst[(long)t * 64] = __float2bfloat16(x[t]);
      dst[(long)(t + 1) * 64] = __float2bfloat16(x[t + 1]);
      short2 pk; pk.x = f2bsh(x[t]); pk.y = f2bsh(x[t + 1]);
      *(short2*)&XT[colW][t] = pk;
    }
  }
  __syncthreads();   // WT/U0T ready

  // ph10: McT = -(K'^T)(W^T)^T : C[m=k'][n=k] = sum_t KpT[k'][t] WT[k][t]
  {
    f32x4 macc[4] = {};
#pragma unroll
    for (int ks = 0; ks < 2; ++ks) {
      bf16x8 afr = *(const bf16x8*)&KpT[wv * 16 + lm][lk8 + ks * 32];
#pragma unroll
      for (int ni = 0; ni < 4; ++ni) {
        bf16x8 bfr = *(const bf16x8*)&WT[ni * 16 + lm][lk8 + ks * 32];
        macc[ni] = __builtin_amdgcn_mfma_f32_16x16x32_bf16(afr, bfr, macc[ni], 0, 0, 0);
      }
    }
#pragma unroll
    for (int ni = 0; ni < 4; ++ni)
#pragma unroll
      for (int r = 0; r < 4; ++r)
        McT[task * 4096 + (wv * 16 + r0 + r) * 64 + ni * 16 + cn] =
            __float2bfloat16(-macc[ni][r]);
  }
  // Bc : C[m=v][n=k'] = sum_t U0T[v][t] KpT[k'][t]
  {
    f32x4 bacc[4] = {};
#pragma unroll
    for (int ks = 0; ks < 2; ++ks) {
      bf16x8 afr = *(const bf16x8*)&U0T[wv * 16 + lm][lk8 + ks * 32];
#pragma unroll
      for (int ni = 0; ni < 4; ++ni) {
        bf16x8 bfr = *(const bf16x8*)&KpT[ni * 16 + lm][lk8 + ks * 32];
        bacc[ni] = __builtin_amdgcn_mfma_f32_16x16x32_bf16(afr, bfr, bacc[ni], 0, 0, 0);
      }
    }
#pragma unroll
    for (int ni = 0; ni < 4; ++ni)
#pragma unroll
      for (int r = 0; r < 4; ++r)
        Bc[task * 4096 + (wv * 16 + r0 + r) * 64 + ni * 16 + cn] =
            __float2bfloat16(bacc[ni][r]);
  }
}

// ---------------------------------------------------------------------------
// chunk_state (r6-validated): serial recurrence, 4 chunks per barrier-group,
// T14 async split (regs->LDS write-late, loads issued 2 groups ahead).
// ---------------------------------------------------------------------------
__global__ __launch_bounds__(256) void chunk_state(const bf16* __restrict__ McT,
                                                   const bf16* __restrict__ Bc,
                                                   const float* __restrict__ lgws,
                                                   bf16* __restrict__ Sb) {
  __shared__ short Msm[2][4][64][72];
  __shared__ short Bsm[2][4][64][72];
  __shared__ short Ssm[64][72];   // bf16 state rows [v][k] (wave-private bands)
  __shared__ float lgsm[2][4];

  const int hb = blockIdx.x;      // b*16+h
  const int tid = threadIdx.x, wv = tid >> 6, l = tid & 63;
  const int lm = l & 15, lk8 = (l >> 4) << 3;
  const int r0 = (l >> 4) << 2, cn = l & 15;
  const int srow = tid >> 2, scol = (tid & 3) * 16;

  for (int i = tid; i < 64 * 72; i += 256) ((short*)Ssm)[i] = 0;
  f32x4 Sreg[4] = {};   // fp32 master: S[v = wv*16+r0+r][k = ni*16+cn]

  // next-group staging registers (4 chunks x (M,B) x 2 bf16x8 = 64 VGPRs)
  bf16x8 mr0[4], mr1[4], br0[4], br1[4];
  float lgn0, lgn1, lgn2, lgn3;

  auto gload = [&](int g) {   // issue global loads for group g into regs
#pragma unroll
    for (int cc = 0; cc < 4; ++cc) {
      const long tt = (long)hb * 64 + g * 4 + cc;
      const bf16* mp = McT + tt * 4096 + srow * 64 + scol;
      const bf16* bp = Bc + tt * 4096 + srow * 64 + scol;
      mr0[cc] = *(const bf16x8*)(mp);
      mr1[cc] = *(const bf16x8*)(mp + 8);
      br0[cc] = *(const bf16x8*)(bp);
      br1[cc] = *(const bf16x8*)(bp + 8);
    }
    const long tb = (long)hb * 64 + g * 4;
    lgn0 = lgws[(tb + 0) * 64 + 63];
    lgn1 = lgws[(tb + 1) * 64 + 63];
    lgn2 = lgws[(tb + 2) * 64 + 63];
    lgn3 = lgws[(tb + 3) * 64 + 63];
  };
  auto lwrite = [&](int g) {  // regs -> LDS buffer g&1
    const int bu = g & 1;
#pragma unroll
    for (int cc = 0; cc < 4; ++cc) {
      *(bf16x8*)&Msm[bu][cc][srow][scol]     = mr0[cc];
      *(bf16x8*)&Msm[bu][cc][srow][scol + 8] = mr1[cc];
      *(bf16x8*)&Bsm[bu][cc][srow][scol]     = br0[cc];
      *(bf16x8*)&Bsm[bu][cc][srow][scol + 8] = br1[cc];
    }
    if (tid == 0) {
      lgsm[bu][0] = lgn0; lgsm[bu][1] = lgn1;
      lgsm[bu][2] = lgn2; lgsm[bu][3] = lgn3;
    }
  };

  gload(0);
  lwrite(0);
  gload(1);
  __syncthreads();   // buffer 0 ready; group-1 loads drained (prologue cost)

  for (int g = 0; g < 16; ++g) {
    const int bu = g & 1;
    if (g + 1 < 16) lwrite(g + 1);   // regs (drained at prev barrier) -> LDS
    if (g + 2 < 16) gload(g + 2);    // issue early; hidden under 4-chunk compute
#pragma unroll
    for (int cc = 0; cc < 4; ++cc) {
      const int c = g * 4 + cc;
      // boundary state S_c (pre-update) -> global; off critical path
      {
        bf16* sp = Sb + ((long)hb * 64 + c) * 4096;
#pragma unroll
        for (int ni = 0; ni < 4; ++ni)
#pragma unroll
          for (int r = 0; r < 4; ++r)
            sp[(wv * 16 + r0 + r) * 64 + ni * 16 + cn] = __float2bfloat16(Sreg[ni][r]);
      }
      bf16x8 sfr0 = *(const bf16x8*)&Ssm[wv * 16 + lm][lk8];
      bf16x8 sfr1 = *(const bf16x8*)&Ssm[wv * 16 + lm][lk8 + 32];
      f32x4 kacc[4] = {};
#pragma unroll
      for (int ni = 0; ni < 4; ++ni) {
        bf16x8 b0 = *(const bf16x8*)&Msm[bu][cc][ni * 16 + lm][lk8];
        kacc[ni] = __builtin_amdgcn_mfma_f32_16x16x32_bf16(sfr0, b0, kacc[ni], 0, 0, 0);
        bf16x8 b1 = *(const bf16x8*)&Msm[bu][cc][ni * 16 + lm][lk8 + 32];
        kacc[ni] = __builtin_amdgcn_mfma_f32_16x16x32_bf16(sfr1, b1, kacc[ni], 0, 0, 0);
      }
      const float eend = __expf(lgsm[bu][cc]);
#pragma unroll
      for (int ni = 0; ni < 4; ++ni)
#pragma unroll
        for (int r = 0; r < 4; ++r) {
          const float bv = bsh2f(Bsm[bu][cc][wv * 16 + r0 + r][ni * 16 + cn]);
          Sreg[ni][r] = eend * Sreg[ni][r] + kacc[ni][r] + bv;
          Ssm[wv * 16 + r0 + r][ni * 16 + cn] = f2bsh(Sreg[ni][r]);
        }
    }
    __syncthreads();   // group g reads done; g+1 LDS writes + g+2 loads drained
  }
}

// ---------------------------------------------------------------------------
// chunk_out (r2-validated): fully parallel over 2048 (b,h,chunk) tasks.
//   A[t,i]  = (q_t.k_i) * exp(lg_t - lg_i), i<=t
//   Dt[v,t] = U0[t,v] - (S0v . W^T)[v,t]
//   O[t,v]  = (e^{lg} q)_t . S0v  +  A . Dt
// ---------------------------------------------------------------------------
__global__ __launch_bounds__(256) void chunk_out(const bf16* __restrict__ qkv,
                                                 const bf16* __restrict__ Wws,
                                                 const bf16* __restrict__ U0ws,
                                                 const float* __restrict__ lgws,
                                                 const bf16* __restrict__ Sb,
                                                 float* __restrict__ o) {
  __shared__ short Qsm[64][72];   // q rows (later scaled in place by exp(lg_t))
  __shared__ short Ksm[64][72];   // k rows
  __shared__ short Wsm[64][72];   // W rows [t][dk]
  __shared__ short Usm[64][72];   // U0 rows [t][v]
  __shared__ short Amm[64][72];   // A rows [t][i]
  __shared__ short Dsm[64][72];   // Dt rows [v][t] (wave-private 16-row bands)
  __shared__ float lgs[64];

  const int blk = blockIdx.x;
  const int hb = blk & 31, c = blk >> 5;      // hb fast: qkv-row L2 reuse
  const long task = (long)hb * 64 + c;
  const int h = hb & 15, b = hb >> 4, kh = h >> 1;
  const long sb = (long)b * S_ + (long)c * CS_;
  const int tid = threadIdx.x, wv = tid >> 6, l = tid & 63;
  const int lm = l & 15, lk8 = (l >> 4) << 3;
  const int r0 = (l >> 4) << 2, cn = l & 15;
  const int srow = tid >> 2, scol = (tid & 3) * 16;

  // S0 fragments straight from global (L2-resident after chunk_state).
  const bf16* sp = Sb + task * 4096 + (wv * 16 + lm) * 64 + lk8;
  bf16x8 sfr0 = *(const bf16x8*)(sp);
  bf16x8 sfr1 = *(const bf16x8*)(sp + 32);

  {
    const bf16* qp = qkv + (sb + srow) * CDIM_ + kh * 64 + scol;
    const bf16* kp = qkv + (sb + srow) * CDIM_ + KEYD_ + kh * 64 + scol;
    const bf16* wp = Wws + task * 4096 + srow * 64 + scol;
    const bf16* up = U0ws + task * 4096 + srow * 64 + scol;
    *(bf16x8*)&Qsm[srow][scol]     = *(const bf16x8*)(qp);
    *(bf16x8*)&Qsm[srow][scol + 8] = *(const bf16x8*)(qp + 8);
    *(bf16x8*)&Ksm[srow][scol]     = *(const bf16x8*)(kp);
    *(bf16x8*)&Ksm[srow][scol + 8] = *(const bf16x8*)(kp + 8);
    *(bf16x8*)&Wsm[srow][scol]     = *(const bf16x8*)(wp);
    *(bf16x8*)&Wsm[srow][scol + 8] = *(const bf16x8*)(wp + 8);
    *(bf16x8*)&Usm[srow][scol]     = *(const bf16x8*)(up);
    *(bf16x8*)&Usm[srow][scol + 8] = *(const bf16x8*)(up + 8);
    if (tid < 64) lgs[tid] = lgws[task * 64 + tid];
  }
  __syncthreads();

  // A matrix: wave computes its 16 t-rows x all i.
  {
    f32x4 aacc[4] = {};
#pragma unroll
    for (int ks = 0; ks < 2; ++ks) {
      bf16x8 qa = *(const bf16x8*)&Qsm[wv * 16 + lm][lk8 + ks * 32];
#pragma unroll
      for (int ni = 0; ni < 4; ++ni) {
        bf16x8 kb = *(const bf16x8*)&Ksm[ni * 16 + lm][lk8 + ks * 32];
        aacc[ni] = __builtin_amdgcn_mfma_f32_16x16x32_bf16(qa, kb, aacc[ni], 0, 0, 0);
      }
    }
#pragma unroll
    for (int ni = 0; ni < 4; ++ni)
#pragma unroll
      for (int r = 0; r < 4; ++r) {
        const int t = wv * 16 + r0 + r, i = ni * 16 + cn;
        Amm[t][i] = f2bsh((i <= t) ? aacc[ni][r] * __expf(lgs[t] - lgs[i]) : 0.f);
      }
  }
  __syncthreads();  // all A-reads of Qsm done; now safe to scale Q in place

  {
    const float sc = __expf(lgs[srow]);       // Lambda_t
#pragma unroll
    for (int j = 0; j < 16; ++j)
      Qsm[srow][scol + j] = f2bsh(sc * bsh2f(Qsm[srow][scol + j]));
  }
  __syncthreads();

  // M1: Dt[v,t] = U0[t,v] - sum_k S0v[v,k] W[t,k]
  {
    f32x4 dacc[4] = {};
#pragma unroll
    for (int ni = 0; ni < 4; ++ni) {
      bf16x8 w0 = *(const bf16x8*)&Wsm[ni * 16 + lm][lk8];
      dacc[ni] = __builtin_amdgcn_mfma_f32_16x16x32_bf16(sfr0, w0, dacc[ni], 0, 0, 0);
      bf16x8 w1 = *(const bf16x8*)&Wsm[ni * 16 + lm][lk8 + 32];
      dacc[ni] = __builtin_amdgcn_mfma_f32_16x16x32_bf16(sfr1, w1, dacc[ni], 0, 0, 0);
    }
#pragma unroll
    for (int ni = 0; ni < 4; ++ni)
#pragma unroll
      for (int r = 0; r < 4; ++r) {
        const int t = ni * 16 + cn, v = r0 + r;
        Dsm[wv * 16 + v][t] = f2bsh(bsh2f(Usm[t][wv * 16 + v]) - dacc[ni][r]);
      }
  }
  // wave-private Dsm: in-wave ds ordering + compiler lgkmcnt suffice (no barrier)
  bf16x8 dfr0 = *(const bf16x8*)&Dsm[wv * 16 + lm][lk8];
  bf16x8 dfr1 = *(const bf16x8*)&Dsm[wv * 16 + lm][lk8 + 32];

  // M2+M3: O[t, v16] = LambdaQ . S0v + A . Dt
  {
    f32x4 oacc[4] = {};
#pragma unroll
    for (int mi = 0; mi < 4; ++mi) {
      bf16x8 q0 = *(const bf16x8*)&Qsm[mi * 16 + lm][lk8];
      oacc[mi] = __builtin_amdgcn_mfma_f32_16x16x32_bf16(q0, sfr0, oacc[mi], 0, 0, 0);
      bf16x8 q1 = *(const bf16x8*)&Qsm[mi * 16 + lm][lk8 + 32];
      oacc[mi] = __builtin_amdgcn_mfma_f32_16x16x32_bf16(q1, sfr1, oacc[mi], 0, 0, 0);
    }
#pragma unroll
    for (int mi = 0; mi < 4; ++mi) {
      bf16x8 a0 = *(const bf16x8*)&Amm[mi * 16 + lm][lk8];
      oacc[mi] = __builtin_amdgcn_mfma_f32_16x16x32_bf16(a0, dfr0, oacc[mi], 0, 0, 0);
      bf16x8 a1 = *(const bf16x8*)&Amm[mi * 16 + lm][lk8 + 32];
      oacc[mi] = __builtin_amdgcn_mfma_f32_16x16x32_bf16(a1, dfr1, oacc[mi], 0, 0, 0);
    }
#pragma unroll
    for (int mi = 0; mi < 4; ++mi)
#pragma unroll
      for (int r = 0; r < 4; ++r) {
        const int t = mi * 16 + r0 + r;
        o[(sb + t) * VALD_ + h * 64 + wv * 16 + cn] = oacc[mi][r];
      }
  }
}

// ---------------------------------------------------------------------------
// gnorm3 (r5-validated): h = o*silu(z); rmsnorm; *w -> bf16 hn. Vectorized.
// ---------------------------------------------------------------------------
__global__ __launch_bounds__(256) void gnorm3(const float* __restrict__ o,
                                              const float* __restrict__ z,
                                              const float* __restrict__ nw,
                                              bf16* __restrict__ hn) {
  const long idx = (long)blockIdx.x * 256 + threadIdx.x;  // M*16
  const float* op = o + idx * 64;
  const float* zp = z + idx * 64;
  float4 hv[16];
  float ss = 0.f;
#pragma unroll
  for (int i = 0; i < 16; ++i) {
    const float4 ov = *(const float4*)(op + i * 4);
    const float4 zv = *(const float4*)(zp + i * 4);
    float4 h;
    h.x = ov.x * (zv.x / (1.f + __expf(-zv.x)));
    h.y = ov.y * (zv.y / (1.f + __expf(-zv.y)));
    h.z = ov.z * (zv.z / (1.f + __expf(-zv.z)));
    h.w = ov.w * (zv.w / (1.f + __expf(-zv.w)));
    hv[i] = h;
    ss = fmaf(h.x, h.x, ss); ss = fmaf(h.y, h.y, ss);
    ss = fmaf(h.z, h.z, ss); ss = fmaf(h.w, h.w, ss);
  }
  const float r = rsqrtf(ss * (1.f / 64.f) + 1e-6f);
#pragma unroll
  for (int i = 0; i < 16; i += 2) {
    const float4 w0 = *(const float4*)(nw + i * 4);
    const float4 w1 = *(const float4*)(nw + i * 4 + 4);
    bf16x8 pk;
    pk[0] = f2bsh(hv[i].x * r * w0.x);     pk[1] = f2bsh(hv[i].y * r * w0.y);
    pk[2] = f2bsh(hv[i].z * r * w0.z);     pk[3] = f2bsh(hv[i].w * r * w0.w);
    pk[4] = f2bsh(hv[i + 1].x * r * w1.x); pk[5] = f2bsh(hv[i + 1].y * r * w1.y);
    pk[6] = f2bsh(hv[i + 1].z * r * w1.z); pk[7] = f2bsh(hv[i + 1].w * r * w1.w);
    *(bf16x8*)((uint16_t*)hn + idx * 64 + i * 4) = pk;
  }
}

// ---------------------------------------------------------------------------
extern "C" void kernel_launch(void* const* d_in, const int* in_sizes, int n_in,
                              void* d_out, int out_size, void* d_ws, size_t ws_size,
                              hipStream_t stream) {
  float* out = (float*)d_out;   // fp32 output (r8-confirmed)
  const int M = B_ * S_;        // 8192

  // input mapping (dict order confirmed; size-based fallback kept)
  int ih, iqkv, icw, iz, ib, ia, idtb, ialog, inw, iout;
  if (n_in >= 10 && in_sizes[0] == 8388608) {
    ih = 0; iqkv = 1; icw = 2; iz = 3; ib = 4; ia = 5;
    idtb = 6; ialog = 7; inw = 8; iout = 9;
  } else {
    ih = iqkv = icw = iz = ib = ia = idtb = ialog = inw = iout = -1;
    for (int i = 0; i < n_in; ++i) {
      switch (in_sizes[i]) {
        case 8388608: ih = i; break;
        case 2097152: iqkv = i; break;
        case 8192:    icw = i; break;
        case 64:      inw = i; break;
        case 1048576: if (iz < 0) iz = i; else iout = i; break;
        case 16384:   if (ib < 0) ib = i; else ia = i; break;
        case 16:      if (idtb < 0) idtb = i; else ialog = i; break;
        default: break;
      }
    }
  }
  const float* hs   = (const float*)d_in[ih];
  const float* Wqkv = (const float*)d_in[iqkv];
  const float* cw   = (const float*)d_in[icw];
  const float* Wz   = (const float*)d_in[iz];
  const float* Wb   = (const float*)d_in[ib];
  const float* Wa   = (const float*)d_in[ia];
  const float* dtb  = (const float*)d_in[idtb];
  const float* Alog = (const float*)d_in[ialog];
  const float* nwv  = (const float*)d_in[inw];
  const float* Wout = (const float*)d_in[iout];

  // workspace (~122 MiB): r2 layout; Mc/Bc alias region1 (mixed dead after
  // conv; of not written until chunk_out).
  char* p = (char*)d_ws;
  bf16*  mixed = (bf16*)p;                                 // region1: 32 MiB
  float* of    = (float*)p;                                //   of aliases mixed
  bf16*  McTw  = (bf16*)p;                                 //   McT: first 16 MiB
  bf16*  Bcw   = (bf16*)(p + (size_t)2048 * 4096 * 2);     //   Bc: second 16 MiB
  p += (size_t)M * CDIM_ * 2;
  bf16*  hs_b  = (bf16*)p;                                 // region2 (16 MiB; dead after z-gemm)
  bf16*  qkvb  = (bf16*)p;                                 //   full region2
  bf16*  hn    = (bf16*)p; p += (size_t)M * CDIM_ * 2;     //   hn aliases qkvb
  bf16*  Wqkv_b= (bf16*)p; p += (size_t)CDIM_ * H_ * 2;    // 4 MiB
  bf16*  Wz_b  = (bf16*)p; p += (size_t)H_ * H_ * 2;       // 2 MiB
  bf16*  Wout_b= (bf16*)p; p += (size_t)H_ * H_ * 2;       // 2 MiB
  float* betaf = (float*)p; p += (size_t)M * NVH_ * 4;     // 512 KiB
  float* gf    = (float*)p; p += (size_t)M * NVH_ * 4;     // 512 KiB
  bf16*  Wws   = (bf16*)p; p += (size_t)2048 * 4096 * 2;   // 16 MiB
  bf16*  U0ws  = (bf16*)p; p += (size_t)2048 * 4096 * 2;   // 16 MiB
  float* lgws  = (float*)p; p += (size_t)2048 * 64 * 4;    // 512 KiB
  bf16*  Sbw   = (bf16*)p; p += (size_t)2048 * 4096 * 2;   // 16 MiB (boundary states)
  float* zb    = out;   // z fp32 staged in d_out, consumed by gnorm3

  // 0) casts fp32 -> bf16 for MFMA operands
  {
    long n;
    n = (long)M * H_;     castf2b<<<(int)(n / 4 / 256), 256, 0, stream>>>(hs,   hs_b,   n);
    n = (long)CDIM_ * H_; castf2b<<<(int)(n / 4 / 256), 256, 0, stream>>>(Wqkv, Wqkv_b, n);
    n = (long)H_ * H_;    castf2b<<<(int)(n / 4 / 256), 256, 0, stream>>>(Wz,   Wz_b,   n);
    n = (long)H_ * H_;    castf2b<<<(int)(n / 4 / 256), 256, 0, stream>>>(Wout, Wout_b, n);
  }
  // 1) mixed = hs @ Wqkv^T  [8192 x 2048] -> bf16 (MFMA)
  gemm_bt<bf16><<<(M / 128) * (CDIM_ / 128), 256, 0, stream>>>(hs_b, Wqkv_b, mixed, M, CDIM_, H_);
  // 2) z = hs @ Wz^T  [8192 x 1024] -> fp32 in d_out (MFMA)
  gemm_bt<float><<<(M / 128) * (H_ / 128), 256, 0, stream>>>(hs_b, Wz_b, zb, M, H_, H_);
  // 3) beta, g (8 rows per block)
  proj_ba2<<<M / 8, 256, 0, stream>>>(hs, Wb, Wa, dtb, Alog, betaf, gf);
  // 4) causal depthwise conv + silu + q-scale -> bf16 (8 ch/thread vectorized)
  conv3<<<(int)(((long)M * CDIM_) / 8 / 256), 256, 0, stream>>>(mixed, cw, qkvb);
  // 5) chunked delta-rule, decoupled:
  //    a) UT-transform precompute + affine transition pieces (fused; 2048 WGs)
  chunk_pre<<<2048, 256, 0, stream>>>(qkvb, betaf, gf, Wws, U0ws, lgws, McTw, Bcw);
  //    b) serial boundary-state recurrence (32 WGs, 4 chunks/barrier-group)
  chunk_state<<<32, 256, 0, stream>>>(McTw, Bcw, lgws, Sbw);
  //    c) per-chunk outputs (parallel 2048)
  chunk_out<<<2048, 256, 0, stream>>>(qkvb, Wws, U0ws, lgws, Sbw, of);
  // 6) gated RMSNorm -> hn bf16 (vectorized)
  gnorm3<<<(M * NVH_) / 256, 256, 0, stream>>>(of, zb, nwv, hn);
  // 7) out = hn @ Wout^T -> d_out fp32 (MFMA)
  gemm_bt<float><<<(M / 128) * (H_ / 128), 256, 0, stream>>>(hn, Wout_b, out, M, H_, H_);
}

// Round 8
// 477.628 us; speedup vs baseline: 1.0657x; 1.0657x over previous
//
#include <hip/hip_runtime.h>
#include <hip/hip_bf16.h>
#include <stdint.h>

// Problem constants
#define B_    2
#define S_    4096
#define H_    1024
#define NKH_  8
#define NVH_  16
#define DK_   64
#define DV_   64
#define KEYD_ 512          // NKH*DK
#define CDIM_ 2048         // 2*KEYD + VAL_DIM
#define VALD_ 1024         // NVH*DV
#define NCHUNK_ 64         // S_/64
#define CS_   64           // chunk size

using bf16 = __hip_bfloat16;
using bf16x8 = __attribute__((ext_vector_type(8))) short;  // 8 bf16 = 4 VGPRs
using f32x4  = __attribute__((ext_vector_type(4))) float;

__device__ inline float bsh2f(short s) {
  union { ushort u; bf16 h; } c; c.u = (ushort)s; return __bfloat162float(c.h);
}
__device__ inline short f2bsh(float f) {
  union { ushort u; bf16 h; } c; c.h = __float2bfloat16(f); return (short)c.u;
}

// async global->LDS, 16B per lane; dest = uniform base + lane*16 (HW rule).
__device__ __forceinline__ void gload16(const bf16* g, short* lds) {
  __builtin_amdgcn_global_load_lds(
      (const __attribute__((address_space(1))) void*)g,
      (__attribute__((address_space(3))) void*)lds, 16, 0, 0);
}

// ---------------------------------------------------------------------------
// 32x32 fp32 forward-substitution on register-resident column x, rows
// [BASE, BASE+32). BASE is a TEMPLATE parameter so every x[] index is a
// compile-time constant after unrolling (rule #20: runtime-indexed register
// arrays go to scratch — r7's regression, FETCH 20K->61K, VGPR 88->68).
// ---------------------------------------------------------------------------
template <int BASE>
__device__ __forceinline__ void solve32_reg(float (&x)[64],
                                            const float (*T)[64]) {
#pragma unroll
  for (int jj = 0; jj < 32; jj += 8) {
    const int j = BASE + jj;
    float xs[8];
#pragma unroll
    for (int a = 0; a < 8; ++a) xs[a] = x[j + a];
#pragma unroll
    for (int a = 1; a < 8; ++a)
#pragma unroll
      for (int bb = 0; bb < a; ++bb)
        xs[a] = fmaf(-T[j + a][j + bb], xs[bb], xs[a]);
#pragma unroll
    for (int a = 1; a < 8; ++a) x[j + a] = xs[a];
#pragma unroll
    for (int t2 = jj + 8; t2 < 32; ++t2) {
      const int tt = BASE + t2;
      const float4 ta = *(const float4*)&T[tt][j];
      const float4 tb = *(const float4*)&T[tt][j + 4];
      float v = x[tt];
      v = fmaf(-ta.x, xs[0], v); v = fmaf(-ta.y, xs[1], v);
      v = fmaf(-ta.z, xs[2], v); v = fmaf(-ta.w, xs[3], v);
      v = fmaf(-tb.x, xs[4], v); v = fmaf(-tb.y, xs[5], v);
      v = fmaf(-tb.z, xs[6], v); v = fmaf(-tb.w, xs[7], v);
      x[tt] = v;
    }
  }
}

// ---------------------------------------------------------------------------
// fp32 -> bf16 cast, 4 elems/thread (n % 4 == 0). (r2-validated structure)
// ---------------------------------------------------------------------------
__global__ __launch_bounds__(256) void castf2b(const float* __restrict__ x,
                                               bf16* __restrict__ y, long n) {
  const long i = ((long)blockIdx.x * 256 + threadIdx.x) * 4;
  if (i >= n) return;
  float4 v = *(const float4*)(x + i);
  union { ushort4 u; bf16 h[4]; } o;
  o.h[0] = __float2bfloat16(v.x);
  o.h[1] = __float2bfloat16(v.y);
  o.h[2] = __float2bfloat16(v.z);
  o.h[3] = __float2bfloat16(v.w);
  *(ushort4*)(y + i) = o.u;
}

// ---------------------------------------------------------------------------
// MFMA GEMM (r4-validated): C[m,n] = sum_k A[m,k]*B[n,k]; A,B bf16;
// C bf16 or fp32. 128x128 tile, 4 waves 2x2, 4x4 of 16x16x32 MFMA, BK=32.
// Staging via global_load_lds width=16 (m97 ladder step-3).
// ---------------------------------------------------------------------------
template <typename OT>
__global__ __launch_bounds__(256) void gemm_bt(const bf16* __restrict__ A,
                                               const bf16* __restrict__ Bm,
                                               OT* __restrict__ C,
                                               int M, int N, int K) {
  __shared__ short Asm[128 * 32];
  __shared__ short Bsm[128 * 32];
  const int t = threadIdx.x;
  const int w = t >> 6, l = t & 63;
  const int ntn = N >> 7;
  const int bm = blockIdx.x / ntn, bn = blockIdx.x % ntn;
  const int m0 = bm << 7, n0 = bn << 7;
  const int wm = (w >> 1) << 6, wn = (w & 1) << 6;

  f32x4 acc[4][4] = {};

  const int grow = l >> 2;            // 0..15 within slab
  const int gc8 = (l & 3) << 3;       // 0,8,16,24
  const bf16* Agl = A + (long)m0 * K + gc8;
  const bf16* Bgl = Bm + (long)n0 * K + gc8;

  const int lm = l & 15;
  const int kk = (l >> 4) << 3;
  const short* ar0 = &Asm[(wm + lm) * 32 + kk];
  const short* br0 = &Bsm[(wn + lm) * 32 + kk];

  for (int k0 = 0; k0 < K; k0 += 32) {
    __syncthreads();   // prev-iter LDS reads done
#pragma unroll
    for (int j = 0; j < 2; ++j) {
      const int s = w * 2 + j;        // slab 0..7 (wave-uniform)
      gload16(Agl + (long)(s * 16 + grow) * K + k0, &Asm[s * 16 * 32]);
      gload16(Bgl + (long)(s * 16 + grow) * K + k0, &Bsm[s * 16 * 32]);
    }
    __syncthreads();   // compiler drains vmcnt before barrier -> LDS ready
    bf16x8 af[4], bfr[4];
#pragma unroll
    for (int mi = 0; mi < 4; ++mi) af[mi] = *(const bf16x8*)(ar0 + mi * 16 * 32);
#pragma unroll
    for (int ni = 0; ni < 4; ++ni) bfr[ni] = *(const bf16x8*)(br0 + ni * 16 * 32);
#pragma unroll
    for (int mi = 0; mi < 4; ++mi)
#pragma unroll
      for (int ni = 0; ni < 4; ++ni)
        acc[mi][ni] = __builtin_amdgcn_mfma_f32_16x16x32_bf16(af[mi], bfr[ni],
                                                              acc[mi][ni], 0, 0, 0);
  }

  // C/D layout: col = l&15, row = (l>>4)*4 + reg
  const int r0 = (l >> 4) << 2;
  const int cn = l & 15;
#pragma unroll
  for (int mi = 0; mi < 4; ++mi)
#pragma unroll
    for (int ni = 0; ni < 4; ++ni) {
      long base = (long)(m0 + wm + mi * 16 + r0) * N + (n0 + wn + ni * 16 + cn);
#pragma unroll
      for (int r = 0; r < 4; ++r) {
        if constexpr (sizeof(OT) == 2)
          C[base + (long)r * N] = __float2bfloat16(acc[mi][ni][r]);
        else
          C[base + (long)r * N] = acc[mi][ni][r];
      }
    }
}

// ---------------------------------------------------------------------------
// conv3 (r5-validated): causal depthwise k=4 conv + silu + q-scale, 8 ch/thr.
// ---------------------------------------------------------------------------
__global__ __launch_bounds__(256) void conv3(const bf16* __restrict__ mixed,
                                             const float* __restrict__ cw,
                                             bf16* __restrict__ qkv) {
  const long idx = (long)blockIdx.x * 256 + threadIdx.x;  // over M*256 groups
  const int c0 = (int)(idx & 255) << 3;                   // channel group base
  const long row = idx >> 8;
  const int s = (int)(row & (S_ - 1));

  bf16x8 mv[4];
#pragma unroll
  for (int j = 0; j < 4; ++j) {
    if (s - 3 + j >= 0)
      mv[j] = *(const bf16x8*)(mixed + (row + j - 3) * CDIM_ + c0);
    else
      mv[j] = (bf16x8){0, 0, 0, 0, 0, 0, 0, 0};
  }

  const float qs = (c0 < KEYD_) ? 0.125f : 1.f;
  union { ushort4 u4[2]; short h[8]; } o;
#pragma unroll
  for (int e = 0; e < 8; ++e) {
    const float4 w = *(const float4*)(cw + (c0 + e) * 4);
    float acc = 0.f;
    acc = fmaf(w.x, bsh2f(mv[0][e]), acc);
    acc = fmaf(w.y, bsh2f(mv[1][e]), acc);
    acc = fmaf(w.z, bsh2f(mv[2][e]), acc);
    acc = fmaf(w.w, bsh2f(mv[3][e]), acc);
    const float y = qs * (acc / (1.f + __expf(-acc)));    // silu (+ q-scale)
    o.h[e] = f2bsh(y);
  }
  *(bf16x8*)((uint16_t*)qkv + row * CDIM_ + c0) = *(bf16x8*)&o.h[0];
}

// ---------------------------------------------------------------------------
// proj_ba2 (r3-validated): 8 rows per block; W traffic cut 8x.
// ---------------------------------------------------------------------------
__global__ __launch_bounds__(256) void proj_ba2(const float* __restrict__ hs,
                                                const float* __restrict__ Wb,
                                                const float* __restrict__ Wa,
                                                const float* __restrict__ dtb,
                                                const float* __restrict__ Alog,
                                                float* __restrict__ beta,
                                                float* __restrict__ g) {
  __shared__ float4 hrow[8][257];   // +1 float4 pad
  const long row0 = (long)blockIdx.x * 8;
  const int tid = threadIdx.x;
  for (int i = tid; i < 2048; i += 256) {
    const int r = i >> 8, c4 = i & 255;
    hrow[r][c4] = *(const float4*)(hs + (row0 + r) * H_ + (long)c4 * 4);
  }
  __syncthreads();
  const int j = tid >> 3, r = tid & 7;
  const float4* Wp = (const float4*)(j < 16 ? Wb + (long)j * H_
                                            : Wa + (long)(j - 16) * H_);
  float4 a4 = {0.f, 0.f, 0.f, 0.f};
#pragma unroll 4
  for (int i = 0; i < 256; ++i) {
    const float4 w = Wp[i];
    const float4 hv = hrow[r][i];
    a4.x = fmaf(w.x, hv.x, a4.x);
    a4.y = fmaf(w.y, hv.y, a4.y);
    a4.z = fmaf(w.z, hv.z, a4.z);
    a4.w = fmaf(w.w, hv.w, a4.w);
  }
  const float acc = (a4.x + a4.y) + (a4.z + a4.w);
  const long row = row0 + r;
  if (j < 16) {
    beta[row * NVH_ + j] = 1.f / (1.f + __expf(-acc));
  } else {
    const int hh = j - 16;
    const float x = acc + dtb[hh];
    const float sp = (x > 20.f) ? x : log1pf(__expf(x));
    g[row * NVH_ + hh] = -__expf(Alog[hh]) * sp;
  }
}

// ---------------------------------------------------------------------------
// chunk_pre (r8): per (b,h,chunk) task:
//   lg = cumsum(g); T[t,i] = beta_t e^{lg_t-lg_i}(k_t.k_i), i<t
//   solve (I+T)X = [diag(beta e^lg)K | diag(beta)V] -> W,U0
//   K' = e^{lg63-lg_t} k; McT = -K'^T W; Bc = U0^T K' (MFMA)
// Register-resident solve with template<BASE> (all x[] indices compile-time
// constant -> truly in VGPRs; r7's runtime-base lambda spilled to scratch).
// LDS 44.8KB => 3 WG/CU.
// ---------------------------------------------------------------------------
__global__ __launch_bounds__(256, 3) void chunk_pre(const bf16* __restrict__ qkv,
                                                    const float* __restrict__ beta,
                                                    const float* __restrict__ g,
                                                    bf16* __restrict__ Wws,
                                                    bf16* __restrict__ U0ws,
                                                    float* __restrict__ lgws,
                                                    bf16* __restrict__ McT,
                                                    bf16* __restrict__ Bc) {
  __shared__ short Ksm[64][72];   // aliased: TloB (ph5), Ucr (ph6-7)
  __shared__ short Vsm[64][72];   // aliased: XB (ph4b-5), U0T (ph9-10)
  __shared__ float Tsm[64][64];   // aliased: WT (ph9-10)
  __shared__ short KpT[64][72];   // K'^T rows [k][t]
  __shared__ float lgs[64];
  __shared__ float bts[64];
  __shared__ float belg[64];

  // aliases (live ranges disjoint; barriers separate read/write phases)
  short (*XB)[36]   = (short (*)[36]) & Vsm[0][0];   // bf16 Xu [col][u], 9216B
  short (*TloB)[40] = (short (*)[40]) & Ksm[0][0];   // bf16 T[32+m][u], 2560B
  short (*UcrB)[68] = (short (*)[68]) & Ksm[0][0];   // bf16 cross-upd [row][col], 4352B
  short (*WT)[72]   = (short (*)[72]) & Tsm[0][0];
  short (*U0T)[72]  = Vsm;

  const int blk = blockIdx.x;
  const int hb = blk & 31, c = blk >> 5;   // hb fast: qkv-row L2 reuse
  const long task = (long)hb * 64 + c;
  const int h = hb & 15, b = hb >> 4, kh = h >> 1;
  const long t0 = (long)b * S_ + (long)c * CS_;
  const int tid = threadIdx.x;
  const int wv = tid >> 6, l = tid & 63;
  const int lm = l & 15, lk8 = (l >> 4) << 3;
  const int r0 = (l >> 4) << 2, cn = l & 15;
  const int srow = tid >> 2, scol = (tid & 3) * 16;

  // ph1: stage K,V
  {
    const bf16* kp = qkv + (t0 + srow) * CDIM_ + KEYD_ + kh * 64 + scol;
    const bf16* vp = qkv + (t0 + srow) * CDIM_ + 2 * KEYD_ + h * 64 + scol;
    *(bf16x8*)&Ksm[srow][scol]     = *(const bf16x8*)(kp);
    *(bf16x8*)&Ksm[srow][scol + 8] = *(const bf16x8*)(kp + 8);
    *(bf16x8*)&Vsm[srow][scol]     = *(const bf16x8*)(vp);
    *(bf16x8*)&Vsm[srow][scol + 8] = *(const bf16x8*)(vp + 8);
  }
  if (tid < 64) {
    bts[tid] = beta[(t0 + tid) * NVH_ + h];
    lgs[tid] = g[(t0 + tid) * NVH_ + h];
  }
  __syncthreads();

  // ph2: wave-parallel inclusive prefix sum of g (wave 0)
  if (tid < 64) {
    float x = lgs[tid];
#pragma unroll
    for (int d = 1; d < 64; d <<= 1) {
      const float y = __shfl_up(x, d);
      if (tid >= d) x += y;
    }
    lgs[tid] = x;
    belg[tid] = bts[tid] * __expf(x);
  }
  __syncthreads();

  // ph3: waves 0-1 KK^T -> T; waves 2-3 K'^T build
  if (tid < 128) {
    f32x4 acc[2][4] = {};
#pragma unroll
    for (int ks = 0; ks < 2; ++ks) {
      bf16x8 bfr[4];
#pragma unroll
      for (int ni = 0; ni < 4; ++ni)
        bfr[ni] = *(const bf16x8*)&Ksm[ni * 16 + lm][lk8 + ks * 32];
#pragma unroll
      for (int mi = 0; mi < 2; ++mi) {
        bf16x8 afr = *(const bf16x8*)&Ksm[(wv * 2 + mi) * 16 + lm][lk8 + ks * 32];
#pragma unroll
        for (int ni = 0; ni < 4; ++ni)
          acc[mi][ni] = __builtin_amdgcn_mfma_f32_16x16x32_bf16(afr, bfr[ni],
                                                                acc[mi][ni], 0, 0, 0);
      }
    }
#pragma unroll
    for (int mi = 0; mi < 2; ++mi)
#pragma unroll
      for (int ni = 0; ni < 4; ++ni)
#pragma unroll
        for (int r = 0; r < 4; ++r) {
          const int t = (wv * 2 + mi) * 16 + r0 + r;
          const int i = ni * 16 + cn;
          Tsm[t][i] = (i < t) ? bts[t] * __expf(lgs[t] - lgs[i]) * acc[mi][ni][r]
                              : 0.f;
        }
  } else {
    const int idx = tid - 128;
    const int tt = idx >> 1;
    const int o2 = (idx & 1) * 32;
    const float dec = __expf(lgs[63] - lgs[tt]);
#pragma unroll 8
    for (int k = 0; k < 32; ++k)
      KpT[o2 + k][tt] = f2bsh(dec * bsh2f(Ksm[tt][o2 + k]));
  }
  __syncthreads();   // Tsm, KpT, belg ready

  // register-resident solution column (threads 0-127)
  float x[64];
  const int colW = tid & 63;
  const bool isW = tid < 64;

  // ph4a: rhs init + upper 32x32 solve (threads 0-127; waves 2-3 idle,
  // co-resident WGs fill the SIMDs at 3 WG/CU)
  if (tid < 128) {
#pragma unroll
    for (int t = 0; t < CS_; ++t)
      x[t] = isW ? belg[t] * bsh2f(Ksm[t][colW])
                 : bts[t] * bsh2f(Vsm[t][colW]);
    solve32_reg<0>(x, Tsm);
  }
  if (tid < 64) lgws[task * 64 + tid] = lgs[tid];
  __syncthreads();   // Ksm/Vsm reads done -> TloB/XB regions writable

  // ph4b: bf16 conversions (owners write XB; waves 2-3 write TloB)
  if (tid < 128) {
#pragma unroll
    for (int p = 0; p < 16; ++p) {
      short2 pk; pk.x = f2bsh(x[2 * p]); pk.y = f2bsh(x[2 * p + 1]);
      *(short2*)&XB[tid][2 * p] = pk;
    }
  } else {
    const int m = (tid - 128) >> 2, u0 = (tid & 3) * 8;
#pragma unroll
    for (int u = 0; u < 8; ++u)
      TloB[m][u0 + u] = f2bsh(Tsm[32 + m][u0 + u]);
  }
  __syncthreads();

  // ph5: rank-32 cross-update via MFMA (all 4 waves, 16 MFMAs)
  f32x4 uacc2[2][2] = {};
  {
#pragma unroll
    for (int ni2 = 0; ni2 < 2; ++ni2) {
      const int ni = wv * 2 + ni2;
      bf16x8 bfr = *(const bf16x8*)&XB[ni * 16 + lm][lk8];
#pragma unroll
      for (int mi = 0; mi < 2; ++mi) {
        bf16x8 afr = *(const bf16x8*)&TloB[mi * 16 + lm][lk8];
        uacc2[ni2][mi] = __builtin_amdgcn_mfma_f32_16x16x32_bf16(afr, bfr,
                                                                 uacc2[ni2][mi], 0, 0, 0);
      }
    }
  }
  __syncthreads();   // TloB reads done -> Ucr (same region) writable

  // ph6: scatter cross-update to owners (bf16)
#pragma unroll
  for (int ni2 = 0; ni2 < 2; ++ni2)
#pragma unroll
    for (int mi = 0; mi < 2; ++mi)
#pragma unroll
      for (int r = 0; r < 4; ++r)
        UcrB[mi * 16 + r0 + r][wv * 32 + ni2 * 16 + cn] = f2bsh(uacc2[ni2][mi][r]);
  __syncthreads();

  // ph7: subtract + lower 32x32 solve (threads 0-127)
  if (tid < 128) {
#pragma unroll
    for (int i = 0; i < 32; ++i)
      x[32 + i] -= bsh2f(UcrB[i][tid]);
    solve32_reg<32>(x, Tsm);
  }
  __syncthreads();   // Tsm reads done -> WT region writable

  // ph9: write W/U0 to global + transposed bf16 into LDS (from registers)
  if (tid < 128) {
    bf16* dst = (isW ? Wws : U0ws) + task * 4096 + colW;
    short (*XT)[72] = isW ? WT : U0T;
#pragma unroll 4
    for (int t = 0; t < CS_; t += 2) {
      dst[(long)t * 64] = __float2bfloat16(x[t]);
      dst[(long)(t + 1) * 64] = __float2bfloat16(x[t + 1]);
      short2 pk; pk.x = f2bsh(x[t]); pk.y = f2bsh(x[t + 1]);
      *(short2*)&XT[colW][t] = pk;
    }
  }
  __syncthreads();   // WT/U0T ready

  // ph10: McT = -(K'^T)(W^T)^T : C[m=k'][n=k] = sum_t KpT[k'][t] WT[k][t]
  {
    f32x4 macc[4] = {};
#pragma unroll
    for (int ks = 0; ks < 2; ++ks) {
      bf16x8 afr = *(const bf16x8*)&KpT[wv * 16 + lm][lk8 + ks * 32];
#pragma unroll
      for (int ni = 0; ni < 4; ++ni) {
        bf16x8 bfr = *(const bf16x8*)&WT[ni * 16 + lm][lk8 + ks * 32];
        macc[ni] = __builtin_amdgcn_mfma_f32_16x16x32_bf16(afr, bfr, macc[ni], 0, 0, 0);
      }
    }
#pragma unroll
    for (int ni = 0; ni < 4; ++ni)
#pragma unroll
      for (int r = 0; r < 4; ++r)
        McT[task * 4096 + (wv * 16 + r0 + r) * 64 + ni * 16 + cn] =
            __float2bfloat16(-macc[ni][r]);
  }
  // Bc : C[m=v][n=k'] = sum_t U0T[v][t] KpT[k'][t]
  {
    f32x4 bacc[4] = {};
#pragma unroll
    for (int ks = 0; ks < 2; ++ks) {
      bf16x8 afr = *(const bf16x8*)&U0T[wv * 16 + lm][lk8 + ks * 32];
#pragma unroll
      for (int ni = 0; ni < 4; ++ni) {
        bf16x8 bfr = *(const bf16x8*)&KpT[ni * 16 + lm][lk8 + ks * 32];
        bacc[ni] = __builtin_amdgcn_mfma_f32_16x16x32_bf16(afr, bfr, bacc[ni], 0, 0, 0);
      }
    }
#pragma unroll
    for (int ni = 0; ni < 4; ++ni)
#pragma unroll
      for (int r = 0; r < 4; ++r)
        Bc[task * 4096 + (wv * 16 + r0 + r) * 64 + ni * 16 + cn] =
            __float2bfloat16(bacc[ni][r]);
  }
}

// ---------------------------------------------------------------------------
// chunk_state (r6-validated): serial recurrence, 4 chunks per barrier-group,
// T14 async split (regs->LDS write-late, loads issued 2 groups ahead).
// ---------------------------------------------------------------------------
__global__ __launch_bounds__(256) void chunk_state(const bf16* __restrict__ McT,
                                                   const bf16* __restrict__ Bc,
                                                   const float* __restrict__ lgws,
                                                   bf16* __restrict__ Sb) {
  __shared__ short Msm[2][4][64][72];
  __shared__ short Bsm[2][4][64][72];
  __shared__ short Ssm[64][72];   // bf16 state rows [v][k] (wave-private bands)
  __shared__ float lgsm[2][4];

  const int hb = blockIdx.x;      // b*16+h
  const int tid = threadIdx.x, wv = tid >> 6, l = tid & 63;
  const int lm = l & 15, lk8 = (l >> 4) << 3;
  const int r0 = (l >> 4) << 2, cn = l & 15;
  const int srow = tid >> 2, scol = (tid & 3) * 16;

  for (int i = tid; i < 64 * 72; i += 256) ((short*)Ssm)[i] = 0;
  f32x4 Sreg[4] = {};   // fp32 master: S[v = wv*16+r0+r][k = ni*16+cn]

  // next-group staging registers (4 chunks x (M,B) x 2 bf16x8 = 64 VGPRs)
  bf16x8 mr0[4], mr1[4], br0[4], br1[4];
  float lgn0, lgn1, lgn2, lgn3;

  auto gload = [&](int g) {   // issue global loads for group g into regs
#pragma unroll
    for (int cc = 0; cc < 4; ++cc) {
      const long tt = (long)hb * 64 + g * 4 + cc;
      const bf16* mp = McT + tt * 4096 + srow * 64 + scol;
      const bf16* bp = Bc + tt * 4096 + srow * 64 + scol;
      mr0[cc] = *(const bf16x8*)(mp);
      mr1[cc] = *(const bf16x8*)(mp + 8);
      br0[cc] = *(const bf16x8*)(bp);
      br1[cc] = *(const bf16x8*)(bp + 8);
    }
    const long tb = (long)hb * 64 + g * 4;
    lgn0 = lgws[(tb + 0) * 64 + 63];
    lgn1 = lgws[(tb + 1) * 64 + 63];
    lgn2 = lgws[(tb + 2) * 64 + 63];
    lgn3 = lgws[(tb + 3) * 64 + 63];
  };
  auto lwrite = [&](int g) {  // regs -> LDS buffer g&1
    const int bu = g & 1;
#pragma unroll
    for (int cc = 0; cc < 4; ++cc) {
      *(bf16x8*)&Msm[bu][cc][srow][scol]     = mr0[cc];
      *(bf16x8*)&Msm[bu][cc][srow][scol + 8] = mr1[cc];
      *(bf16x8*)&Bsm[bu][cc][srow][scol]     = br0[cc];
      *(bf16x8*)&Bsm[bu][cc][srow][scol + 8] = br1[cc];
    }
    if (tid == 0) {
      lgsm[bu][0] = lgn0; lgsm[bu][1] = lgn1;
      lgsm[bu][2] = lgn2; lgsm[bu][3] = lgn3;
    }
  };

  gload(0);
  lwrite(0);
  gload(1);
  __syncthreads();   // buffer 0 ready; group-1 loads drained (prologue cost)

  for (int g = 0; g < 16; ++g) {
    const int bu = g & 1;
    if (g + 1 < 16) lwrite(g + 1);   // regs (drained at prev barrier) -> LDS
    if (g + 2 < 16) gload(g + 2);    // issue early; hidden under 4-chunk compute
#pragma unroll
    for (int cc = 0; cc < 4; ++cc) {
      const int c = g * 4 + cc;
      // boundary state S_c (pre-update) -> global; off critical path
      {
        bf16* sp = Sb + ((long)hb * 64 + c) * 4096;
#pragma unroll
        for (int ni = 0; ni < 4; ++ni)
#pragma unroll
          for (int r = 0; r < 4; ++r)
            sp[(wv * 16 + r0 + r) * 64 + ni * 16 + cn] = __float2bfloat16(Sreg[ni][r]);
      }
      bf16x8 sfr0 = *(const bf16x8*)&Ssm[wv * 16 + lm][lk8];
      bf16x8 sfr1 = *(const bf16x8*)&Ssm[wv * 16 + lm][lk8 + 32];
      f32x4 kacc[4] = {};
#pragma unroll
      for (int ni = 0; ni < 4; ++ni) {
        bf16x8 b0 = *(const bf16x8*)&Msm[bu][cc][ni * 16 + lm][lk8];
        kacc[ni] = __builtin_amdgcn_mfma_f32_16x16x32_bf16(sfr0, b0, kacc[ni], 0, 0, 0);
        bf16x8 b1 = *(const bf16x8*)&Msm[bu][cc][ni * 16 + lm][lk8 + 32];
        kacc[ni] = __builtin_amdgcn_mfma_f32_16x16x32_bf16(sfr1, b1, kacc[ni], 0, 0, 0);
      }
      const float eend = __expf(lgsm[bu][cc]);
#pragma unroll
      for (int ni = 0; ni < 4; ++ni)
#pragma unroll
        for (int r = 0; r < 4; ++r) {
          const float bv = bsh2f(Bsm[bu][cc][wv * 16 + r0 + r][ni * 16 + cn]);
          Sreg[ni][r] = eend * Sreg[ni][r] + kacc[ni][r] + bv;
          Ssm[wv * 16 + r0 + r][ni * 16 + cn] = f2bsh(Sreg[ni][r]);
        }
    }
    __syncthreads();   // group g reads done; g+1 LDS writes + g+2 loads drained
  }
}

// ---------------------------------------------------------------------------
// chunk_out (r2-validated): fully parallel over 2048 (b,h,chunk) tasks.
//   A[t,i]  = (q_t.k_i) * exp(lg_t - lg_i), i<=t
//   Dt[v,t] = U0[t,v] - (S0v . W^T)[v,t]
//   O[t,v]  = (e^{lg} q)_t . S0v  +  A . Dt
// ---------------------------------------------------------------------------
__global__ __launch_bounds__(256) void chunk_out(const bf16* __restrict__ qkv,
                                                 const bf16* __restrict__ Wws,
                                                 const bf16* __restrict__ U0ws,
                                                 const float* __restrict__ lgws,
                                                 const bf16* __restrict__ Sb,
                                                 float* __restrict__ o) {
  __shared__ short Qsm[64][72];   // q rows (later scaled in place by exp(lg_t))
  __shared__ short Ksm[64][72];   // k rows
  __shared__ short Wsm[64][72];   // W rows [t][dk]
  __shared__ short Usm[64][72];   // U0 rows [t][v]
  __shared__ short Amm[64][72];   // A rows [t][i]
  __shared__ short Dsm[64][72];   // Dt rows [v][t] (wave-private 16-row bands)
  __shared__ float lgs[64];

  const int blk = blockIdx.x;
  const int hb = blk & 31, c = blk >> 5;      // hb fast: qkv-row L2 reuse
  const long task = (long)hb * 64 + c;
  const int h = hb & 15, b = hb >> 4, kh = h >> 1;
  const long sb = (long)b * S_ + (long)c * CS_;
  const int tid = threadIdx.x, wv = tid >> 6, l = tid & 63;
  const int lm = l & 15, lk8 = (l >> 4) << 3;
  const int r0 = (l >> 4) << 2, cn = l & 15;
  const int srow = tid >> 2, scol = (tid & 3) * 16;

  // S0 fragments straight from global (L2-resident after chunk_state).
  const bf16* sp = Sb + task * 4096 + (wv * 16 + lm) * 64 + lk8;
  bf16x8 sfr0 = *(const bf16x8*)(sp);
  bf16x8 sfr1 = *(const bf16x8*)(sp + 32);

  {
    const bf16* qp = qkv + (sb + srow) * CDIM_ + kh * 64 + scol;
    const bf16* kp = qkv + (sb + srow) * CDIM_ + KEYD_ + kh * 64 + scol;
    const bf16* wp = Wws + task * 4096 + srow * 64 + scol;
    const bf16* up = U0ws + task * 4096 + srow * 64 + scol;
    *(bf16x8*)&Qsm[srow][scol]     = *(const bf16x8*)(qp);
    *(bf16x8*)&Qsm[srow][scol + 8] = *(const bf16x8*)(qp + 8);
    *(bf16x8*)&Ksm[srow][scol]     = *(const bf16x8*)(kp);
    *(bf16x8*)&Ksm[srow][scol + 8] = *(const bf16x8*)(kp + 8);
    *(bf16x8*)&Wsm[srow][scol]     = *(const bf16x8*)(wp);
    *(bf16x8*)&Wsm[srow][scol + 8] = *(const bf16x8*)(wp + 8);
    *(bf16x8*)&Usm[srow][scol]     = *(const bf16x8*)(up);
    *(bf16x8*)&Usm[srow][scol + 8] = *(const bf16x8*)(up + 8);
    if (tid < 64) lgs[tid] = lgws[task * 64 + tid];
  }
  __syncthreads();

  // A matrix: wave computes its 16 t-rows x all i.
  {
    f32x4 aacc[4] = {};
#pragma unroll
    for (int ks = 0; ks < 2; ++ks) {
      bf16x8 qa = *(const bf16x8*)&Qsm[wv * 16 + lm][lk8 + ks * 32];
#pragma unroll
      for (int ni = 0; ni < 4; ++ni) {
        bf16x8 kb = *(const bf16x8*)&Ksm[ni * 16 + lm][lk8 + ks * 32];
        aacc[ni] = __builtin_amdgcn_mfma_f32_16x16x32_bf16(qa, kb, aacc[ni], 0, 0, 0);
      }
    }
#pragma unroll
    for (int ni = 0; ni < 4; ++ni)
#pragma unroll
      for (int r = 0; r < 4; ++r) {
        const int t = wv * 16 + r0 + r, i = ni * 16 + cn;
        Amm[t][i] = f2bsh((i <= t) ? aacc[ni][r] * __expf(lgs[t] - lgs[i]) : 0.f);
      }
  }
  __syncthreads();  // all A-reads of Qsm done; now safe to scale Q in place

  {
    const float sc = __expf(lgs[srow]);       // Lambda_t
#pragma unroll
    for (int j = 0; j < 16; ++j)
      Qsm[srow][scol + j] = f2bsh(sc * bsh2f(Qsm[srow][scol + j]));
  }
  __syncthreads();

  // M1: Dt[v,t] = U0[t,v] - sum_k S0v[v,k] W[t,k]
  {
    f32x4 dacc[4] = {};
#pragma unroll
    for (int ni = 0; ni < 4; ++ni) {
      bf16x8 w0 = *(const bf16x8*)&Wsm[ni * 16 + lm][lk8];
      dacc[ni] = __builtin_amdgcn_mfma_f32_16x16x32_bf16(sfr0, w0, dacc[ni], 0, 0, 0);
      bf16x8 w1 = *(const bf16x8*)&Wsm[ni * 16 + lm][lk8 + 32];
      dacc[ni] = __builtin_amdgcn_mfma_f32_16x16x32_bf16(sfr1, w1, dacc[ni], 0, 0, 0);
    }
#pragma unroll
    for (int ni = 0; ni < 4; ++ni)
#pragma unroll
      for (int r = 0; r < 4; ++r) {
        const int t = ni * 16 + cn, v = r0 + r;
        Dsm[wv * 16 + v][t] = f2bsh(bsh2f(Usm[t][wv * 16 + v]) - dacc[ni][r]);
      }
  }
  // wave-private Dsm: in-wave ds ordering + compiler lgkmcnt suffice (no barrier)
  bf16x8 dfr0 = *(const bf16x8*)&Dsm[wv * 16 + lm][lk8];
  bf16x8 dfr1 = *(const bf16x8*)&Dsm[wv * 16 + lm][lk8 + 32];

  // M2+M3: O[t, v16] = LambdaQ . S0v + A . Dt
  {
    f32x4 oacc[4] = {};
#pragma unroll
    for (int mi = 0; mi < 4; ++mi) {
      bf16x8 q0 = *(const bf16x8*)&Qsm[mi * 16 + lm][lk8];
      oacc[mi] = __builtin_amdgcn_mfma_f32_16x16x32_bf16(q0, sfr0, oacc[mi], 0, 0, 0);
      bf16x8 q1 = *(const bf16x8*)&Qsm[mi * 16 + lm][lk8 + 32];
      oacc[mi] = __builtin_amdgcn_mfma_f32_16x16x32_bf16(q1, sfr1, oacc[mi], 0, 0, 0);
    }
#pragma unroll
    for (int mi = 0; mi < 4; ++mi) {
      bf16x8 a0 = *(const bf16x8*)&Amm[mi * 16 + lm][lk8];
      oacc[mi] = __builtin_amdgcn_mfma_f32_16x16x32_bf16(a0, dfr0, oacc[mi], 0, 0, 0);
      bf16x8 a1 = *(const bf16x8*)&Amm[mi * 16 + lm][lk8 + 32];
      oacc[mi] = __builtin_amdgcn_mfma_f32_16x16x32_bf16(a1, dfr1, oacc[mi], 0, 0, 0);
    }
#pragma unroll
    for (int mi = 0; mi < 4; ++mi)
#pragma unroll
      for (int r = 0; r < 4; ++r) {
        const int t = mi * 16 + r0 + r;
        o[(sb + t) * VALD_ + h * 64 + wv * 16 + cn] = oacc[mi][r];
      }
  }
}

// ---------------------------------------------------------------------------
// gnorm3 (r5-validated): h = o*silu(z); rmsnorm; *w -> bf16 hn. Vectorized.
// ---------------------------------------------------------------------------
__global__ __launch_bounds__(256) void gnorm3(const float* __restrict__ o,
                                              const float* __restrict__ z,
                                              const float* __restrict__ nw,
                                              bf16* __restrict__ hn) {
  const long idx = (long)blockIdx.x * 256 + threadIdx.x;  // M*16
  const float* op = o + idx * 64;
  const float* zp = z + idx * 64;
  float4 hv[16];
  float ss = 0.f;
#pragma unroll
  for (int i = 0; i < 16; ++i) {
    const float4 ov = *(const float4*)(op + i * 4);
    const float4 zv = *(const float4*)(zp + i * 4);
    float4 h;
    h.x = ov.x * (zv.x / (1.f + __expf(-zv.x)));
    h.y = ov.y * (zv.y / (1.f + __expf(-zv.y)));
    h.z = ov.z * (zv.z / (1.f + __expf(-zv.z)));
    h.w = ov.w * (zv.w / (1.f + __expf(-zv.w)));
    hv[i] = h;
    ss = fmaf(h.x, h.x, ss); ss = fmaf(h.y, h.y, ss);
    ss = fmaf(h.z, h.z, ss); ss = fmaf(h.w, h.w, ss);
  }
  const float r = rsqrtf(ss * (1.f / 64.f) + 1e-6f);
#pragma unroll
  for (int i = 0; i < 16; i += 2) {
    const float4 w0 = *(const float4*)(nw + i * 4);
    const float4 w1 = *(const float4*)(nw + i * 4 + 4);
    bf16x8 pk;
    pk[0] = f2bsh(hv[i].x * r * w0.x);     pk[1] = f2bsh(hv[i].y * r * w0.y);
    pk[2] = f2bsh(hv[i].z * r * w0.z);     pk[3] = f2bsh(hv[i].w * r * w0.w);
    pk[4] = f2bsh(hv[i + 1].x * r * w1.x); pk[5] = f2bsh(hv[i + 1].y * r * w1.y);
    pk[6] = f2bsh(hv[i + 1].z * r * w1.z); pk[7] = f2bsh(hv[i + 1].w * r * w1.w);
    *(bf16x8*)((uint16_t*)hn + idx * 64 + i * 4) = pk;
  }
}

// ---------------------------------------------------------------------------
extern "C" void kernel_launch(void* const* d_in, const int* in_sizes, int n_in,
                              void* d_out, int out_size, void* d_ws, size_t ws_size,
                              hipStream_t stream) {
  float* out = (float*)d_out;   // fp32 output (r8-confirmed)
  const int M = B_ * S_;        // 8192

  // input mapping (dict order confirmed; size-based fallback kept)
  int ih, iqkv, icw, iz, ib, ia, idtb, ialog, inw, iout;
  if (n_in >= 10 && in_sizes[0] == 8388608) {
    ih = 0; iqkv = 1; icw = 2; iz = 3; ib = 4; ia = 5;
    idtb = 6; ialog = 7; inw = 8; iout = 9;
  } else {
    ih = iqkv = icw = iz = ib = ia = idtb = ialog = inw = iout = -1;
    for (int i = 0; i < n_in; ++i) {
      switch (in_sizes[i]) {
        case 8388608: ih = i; break;
        case 2097152: iqkv = i; break;
        case 8192:    icw = i; break;
        case 64:      inw = i; break;
        case 1048576: if (iz < 0) iz = i; else iout = i; break;
        case 16384:   if (ib < 0) ib = i; else ia = i; break;
        case 16:      if (idtb < 0) idtb = i; else ialog = i; break;
        default: break;
      }
    }
  }
  const float* hs   = (const float*)d_in[ih];
  const float* Wqkv = (const float*)d_in[iqkv];
  const float* cw   = (const float*)d_in[icw];
  const float* Wz   = (const float*)d_in[iz];
  const float* Wb   = (const float*)d_in[ib];
  const float* Wa   = (const float*)d_in[ia];
  const float* dtb  = (const float*)d_in[idtb];
  const float* Alog = (const float*)d_in[ialog];
  const float* nwv  = (const float*)d_in[inw];
  const float* Wout = (const float*)d_in[iout];

  // workspace (~122 MiB): r2 layout; Mc/Bc alias region1 (mixed dead after
  // conv; of not written until chunk_out).
  char* p = (char*)d_ws;
  bf16*  mixed = (bf16*)p;                                 // region1: 32 MiB
  float* of    = (float*)p;                                //   of aliases mixed
  bf16*  McTw  = (bf16*)p;                                 //   McT: first 16 MiB
  bf16*  Bcw   = (bf16*)(p + (size_t)2048 * 4096 * 2);     //   Bc: second 16 MiB
  p += (size_t)M * CDIM_ * 2;
  bf16*  hs_b  = (bf16*)p;                                 // region2 (16 MiB; dead after z-gemm)
  bf16*  qkvb  = (bf16*)p;                                 //   full region2
  bf16*  hn    = (bf16*)p; p += (size_t)M * CDIM_ * 2;     //   hn aliases qkvb
  bf16*  Wqkv_b= (bf16*)p; p += (size_t)CDIM_ * H_ * 2;    // 4 MiB
  bf16*  Wz_b  = (bf16*)p; p += (size_t)H_ * H_ * 2;       // 2 MiB
  bf16*  Wout_b= (bf16*)p; p += (size_t)H_ * H_ * 2;       // 2 MiB
  float* betaf = (float*)p; p += (size_t)M * NVH_ * 4;     // 512 KiB
  float* gf    = (float*)p; p += (size_t)M * NVH_ * 4;     // 512 KiB
  bf16*  Wws   = (bf16*)p; p += (size_t)2048 * 4096 * 2;   // 16 MiB
  bf16*  U0ws  = (bf16*)p; p += (size_t)2048 * 4096 * 2;   // 16 MiB
  float* lgws  = (float*)p; p += (size_t)2048 * 64 * 4;    // 512 KiB
  bf16*  Sbw   = (bf16*)p; p += (size_t)2048 * 4096 * 2;   // 16 MiB (boundary states)
  float* zb    = out;   // z fp32 staged in d_out, consumed by gnorm3

  // 0) casts fp32 -> bf16 for MFMA operands
  {
    long n;
    n = (long)M * H_;     castf2b<<<(int)(n / 4 / 256), 256, 0, stream>>>(hs,   hs_b,   n);
    n = (long)CDIM_ * H_; castf2b<<<(int)(n / 4 / 256), 256, 0, stream>>>(Wqkv, Wqkv_b, n);
    n = (long)H_ * H_;    castf2b<<<(int)(n / 4 / 256), 256, 0, stream>>>(Wz,   Wz_b,   n);
    n = (long)H_ * H_;    castf2b<<<(int)(n / 4 / 256), 256, 0, stream>>>(Wout, Wout_b, n);
  }
  // 1) mixed = hs @ Wqkv^T  [8192 x 2048] -> bf16 (MFMA)
  gemm_bt<bf16><<<(M / 128) * (CDIM_ / 128), 256, 0, stream>>>(hs_b, Wqkv_b, mixed, M, CDIM_, H_);
  // 2) z = hs @ Wz^T  [8192 x 1024] -> fp32 in d_out (MFMA)
  gemm_bt<float><<<(M / 128) * (H_ / 128), 256, 0, stream>>>(hs_b, Wz_b, zb, M, H_, H_);
  // 3) beta, g (8 rows per block)
  proj_ba2<<<M / 8, 256, 0, stream>>>(hs, Wb, Wa, dtb, Alog, betaf, gf);
  // 4) causal depthwise conv + silu + q-scale -> bf16 (8 ch/thread vectorized)
  conv3<<<(int)(((long)M * CDIM_) / 8 / 256), 256, 0, stream>>>(mixed, cw, qkvb);
  // 5) chunked delta-rule, decoupled:
  //    a) UT-transform precompute + affine transition pieces (fused; 2048 WGs)
  chunk_pre<<<2048, 256, 0, stream>>>(qkvb, betaf, gf, Wws, U0ws, lgws, McTw, Bcw);
  //    b) serial boundary-state recurrence (32 WGs, 4 chunks/barrier-group)
  chunk_state<<<32, 256, 0, stream>>>(McTw, Bcw, lgws, Sbw);
  //    c) per-chunk outputs (parallel 2048)
  chunk_out<<<2048, 256, 0, stream>>>(qkvb, Wws, U0ws, lgws, Sbw, of);
  // 6) gated RMSNorm -> hn bf16 (vectorized)
  gnorm3<<<(M * NVH_) / 256, 256, 0, stream>>>(of, zb, nwv, hn);
  // 7) out = hn @ Wout^T -> d_out fp32 (MFMA)
  gemm_bt<float><<<(M / 128) * (H_ / 128), 256, 0, stream>>>(hn, Wout_b, out, M, H_, H_);
}

// Round 9
// 459.393 us; speedup vs baseline: 1.1080x; 1.0397x over previous
//
#include <hip/hip_runtime.h>
#include <hip/hip_bf16.h>
#include <stdint.h>

// Problem constants
#define B_    2
#define S_    4096
#define H_    1024
#define NKH_  8
#define NVH_  16
#define DK_   64
#define DV_   64
#define KEYD_ 512          // NKH*DK
#define CDIM_ 2048         // 2*KEYD + VAL_DIM
#define VALD_ 1024         // NVH*DV
#define NCHUNK_ 64         // S_/64
#define CS_   64           // chunk size

using bf16 = __hip_bfloat16;
using bf16x8 = __attribute__((ext_vector_type(8))) short;  // 8 bf16 = 4 VGPRs
using f32x4  = __attribute__((ext_vector_type(4))) float;

__device__ inline float bsh2f(short s) {
  union { ushort u; bf16 h; } c; c.u = (ushort)s; return __bfloat162float(c.h);
}
__device__ inline short f2bsh(float f) {
  union { ushort u; bf16 h; } c; c.h = __float2bfloat16(f); return (short)c.u;
}

// async global->LDS, 16B per lane; dest = uniform base + lane*16 (HW rule).
__device__ __forceinline__ void gload16(const bf16* g, short* lds) {
  __builtin_amdgcn_global_load_lds(
      (const __attribute__((address_space(1))) void*)g,
      (__attribute__((address_space(3))) void*)lds, 16, 0, 0);
}

// ---------------------------------------------------------------------------
// 32x32 fp32 forward-substitution on register-resident column x, rows
// [BASE, BASE+32). BASE is a TEMPLATE parameter so every x[] index is a
// compile-time constant after unrolling (rule #20: runtime-indexed register
// arrays go to scratch — r7/r8 regressions).
// ---------------------------------------------------------------------------
template <int BASE>
__device__ __forceinline__ void solve32_reg(float (&x)[64],
                                            const float (*T)[64]) {
#pragma unroll
  for (int jj = 0; jj < 32; jj += 8) {
    const int j = BASE + jj;
    float xs[8];
#pragma unroll
    for (int a = 0; a < 8; ++a) xs[a] = x[j + a];
#pragma unroll
    for (int a = 1; a < 8; ++a)
#pragma unroll
      for (int bb = 0; bb < a; ++bb)
        xs[a] = fmaf(-T[j + a][j + bb], xs[bb], xs[a]);
#pragma unroll
    for (int a = 1; a < 8; ++a) x[j + a] = xs[a];
#pragma unroll
    for (int t2 = jj + 8; t2 < 32; ++t2) {
      const int tt = BASE + t2;
      const float4 ta = *(const float4*)&T[tt][j];
      const float4 tb = *(const float4*)&T[tt][j + 4];
      float v = x[tt];
      v = fmaf(-ta.x, xs[0], v); v = fmaf(-ta.y, xs[1], v);
      v = fmaf(-ta.z, xs[2], v); v = fmaf(-ta.w, xs[3], v);
      v = fmaf(-tb.x, xs[4], v); v = fmaf(-tb.y, xs[5], v);
      v = fmaf(-tb.z, xs[6], v); v = fmaf(-tb.w, xs[7], v);
      x[tt] = v;
    }
  }
}

// ---------------------------------------------------------------------------
// fp32 -> bf16 cast, 4 elems/thread (n % 4 == 0). (r2-validated structure)
// ---------------------------------------------------------------------------
__global__ __launch_bounds__(256) void castf2b(const float* __restrict__ x,
                                               bf16* __restrict__ y, long n) {
  const long i = ((long)blockIdx.x * 256 + threadIdx.x) * 4;
  if (i >= n) return;
  float4 v = *(const float4*)(x + i);
  union { ushort4 u; bf16 h[4]; } o;
  o.h[0] = __float2bfloat16(v.x);
  o.h[1] = __float2bfloat16(v.y);
  o.h[2] = __float2bfloat16(v.z);
  o.h[3] = __float2bfloat16(v.w);
  *(ushort4*)(y + i) = o.u;
}

// ---------------------------------------------------------------------------
// MFMA GEMM (r4-validated): C[m,n] = sum_k A[m,k]*B[n,k]; A,B bf16;
// C bf16 or fp32. 128x128 tile, 4 waves 2x2, 4x4 of 16x16x32 MFMA, BK=32.
// Staging via global_load_lds width=16 (m97 ladder step-3).
// ---------------------------------------------------------------------------
template <typename OT>
__global__ __launch_bounds__(256) void gemm_bt(const bf16* __restrict__ A,
                                               const bf16* __restrict__ Bm,
                                               OT* __restrict__ C,
                                               int M, int N, int K) {
  __shared__ short Asm[128 * 32];
  __shared__ short Bsm[128 * 32];
  const int t = threadIdx.x;
  const int w = t >> 6, l = t & 63;
  const int ntn = N >> 7;
  const int bm = blockIdx.x / ntn, bn = blockIdx.x % ntn;
  const int m0 = bm << 7, n0 = bn << 7;
  const int wm = (w >> 1) << 6, wn = (w & 1) << 6;

  f32x4 acc[4][4] = {};

  const int grow = l >> 2;            // 0..15 within slab
  const int gc8 = (l & 3) << 3;       // 0,8,16,24
  const bf16* Agl = A + (long)m0 * K + gc8;
  const bf16* Bgl = Bm + (long)n0 * K + gc8;

  const int lm = l & 15;
  const int kk = (l >> 4) << 3;
  const short* ar0 = &Asm[(wm + lm) * 32 + kk];
  const short* br0 = &Bsm[(wn + lm) * 32 + kk];

  for (int k0 = 0; k0 < K; k0 += 32) {
    __syncthreads();   // prev-iter LDS reads done
#pragma unroll
    for (int j = 0; j < 2; ++j) {
      const int s = w * 2 + j;        // slab 0..7 (wave-uniform)
      gload16(Agl + (long)(s * 16 + grow) * K + k0, &Asm[s * 16 * 32]);
      gload16(Bgl + (long)(s * 16 + grow) * K + k0, &Bsm[s * 16 * 32]);
    }
    __syncthreads();   // compiler drains vmcnt before barrier -> LDS ready
    bf16x8 af[4], bfr[4];
#pragma unroll
    for (int mi = 0; mi < 4; ++mi) af[mi] = *(const bf16x8*)(ar0 + mi * 16 * 32);
#pragma unroll
    for (int ni = 0; ni < 4; ++ni) bfr[ni] = *(const bf16x8*)(br0 + ni * 16 * 32);
#pragma unroll
    for (int mi = 0; mi < 4; ++mi)
#pragma unroll
      for (int ni = 0; ni < 4; ++ni)
        acc[mi][ni] = __builtin_amdgcn_mfma_f32_16x16x32_bf16(af[mi], bfr[ni],
                                                              acc[mi][ni], 0, 0, 0);
  }

  // C/D layout: col = l&15, row = (l>>4)*4 + reg
  const int r0 = (l >> 4) << 2;
  const int cn = l & 15;
#pragma unroll
  for (int mi = 0; mi < 4; ++mi)
#pragma unroll
    for (int ni = 0; ni < 4; ++ni) {
      long base = (long)(m0 + wm + mi * 16 + r0) * N + (n0 + wn + ni * 16 + cn);
#pragma unroll
      for (int r = 0; r < 4; ++r) {
        if constexpr (sizeof(OT) == 2)
          C[base + (long)r * N] = __float2bfloat16(acc[mi][ni][r]);
        else
          C[base + (long)r * N] = acc[mi][ni][r];
      }
    }
}

// ---------------------------------------------------------------------------
// conv3 (r5-validated): causal depthwise k=4 conv + silu + q-scale, 8 ch/thr.
// ---------------------------------------------------------------------------
__global__ __launch_bounds__(256) void conv3(const bf16* __restrict__ mixed,
                                             const float* __restrict__ cw,
                                             bf16* __restrict__ qkv) {
  const long idx = (long)blockIdx.x * 256 + threadIdx.x;  // over M*256 groups
  const int c0 = (int)(idx & 255) << 3;                   // channel group base
  const long row = idx >> 8;
  const int s = (int)(row & (S_ - 1));

  bf16x8 mv[4];
#pragma unroll
  for (int j = 0; j < 4; ++j) {
    if (s - 3 + j >= 0)
      mv[j] = *(const bf16x8*)(mixed + (row + j - 3) * CDIM_ + c0);
    else
      mv[j] = (bf16x8){0, 0, 0, 0, 0, 0, 0, 0};
  }

  const float qs = (c0 < KEYD_) ? 0.125f : 1.f;
  union { ushort4 u4[2]; short h[8]; } o;
#pragma unroll
  for (int e = 0; e < 8; ++e) {
    const float4 w = *(const float4*)(cw + (c0 + e) * 4);
    float acc = 0.f;
    acc = fmaf(w.x, bsh2f(mv[0][e]), acc);
    acc = fmaf(w.y, bsh2f(mv[1][e]), acc);
    acc = fmaf(w.z, bsh2f(mv[2][e]), acc);
    acc = fmaf(w.w, bsh2f(mv[3][e]), acc);
    const float y = qs * (acc / (1.f + __expf(-acc)));    // silu (+ q-scale)
    o.h[e] = f2bsh(y);
  }
  *(bf16x8*)((uint16_t*)qkv + row * CDIM_ + c0) = *(bf16x8*)&o.h[0];
}

// ---------------------------------------------------------------------------
// proj_ba2 (r3-validated): 8 rows per block; W traffic cut 8x.
// ---------------------------------------------------------------------------
__global__ __launch_bounds__(256) void proj_ba2(const float* __restrict__ hs,
                                                const float* __restrict__ Wb,
                                                const float* __restrict__ Wa,
                                                const float* __restrict__ dtb,
                                                const float* __restrict__ Alog,
                                                float* __restrict__ beta,
                                                float* __restrict__ g) {
  __shared__ float4 hrow[8][257];   // +1 float4 pad
  const long row0 = (long)blockIdx.x * 8;
  const int tid = threadIdx.x;
  for (int i = tid; i < 2048; i += 256) {
    const int r = i >> 8, c4 = i & 255;
    hrow[r][c4] = *(const float4*)(hs + (row0 + r) * H_ + (long)c4 * 4);
  }
  __syncthreads();
  const int j = tid >> 3, r = tid & 7;
  const float4* Wp = (const float4*)(j < 16 ? Wb + (long)j * H_
                                            : Wa + (long)(j - 16) * H_);
  float4 a4 = {0.f, 0.f, 0.f, 0.f};
#pragma unroll 4
  for (int i = 0; i < 256; ++i) {
    const float4 w = Wp[i];
    const float4 hv = hrow[r][i];
    a4.x = fmaf(w.x, hv.x, a4.x);
    a4.y = fmaf(w.y, hv.y, a4.y);
    a4.z = fmaf(w.z, hv.z, a4.z);
    a4.w = fmaf(w.w, hv.w, a4.w);
  }
  const float acc = (a4.x + a4.y) + (a4.z + a4.w);
  const long row = row0 + r;
  if (j < 16) {
    beta[row * NVH_ + j] = 1.f / (1.f + __expf(-acc));
  } else {
    const int hh = j - 16;
    const float x = acc + dtb[hh];
    const float sp = (x > 20.f) ? x : log1pf(__expf(x));
    g[row * NVH_ + hh] = -__expf(Alog[hh]) * sp;
  }
}

// ---------------------------------------------------------------------------
// chunk_pre (r9): per (b,h,chunk) task:
//   lg = cumsum(g); T[t,i] = beta_t e^{lg_t-lg_i}(k_t.k_i), i<t
//   solve (I+T)X = [diag(beta e^lg)K | diag(beta)V] -> W,U0
//   K' = e^{lg63-lg_t} k; McT = -K'^T W; Bc = U0^T K' (MFMA)
// Register-resident solve. r9 fix: ph9 store loop FULLY unrolled — r8 had
// `#pragma unroll 4` there, leaving x[t] runtime-indexed, which demoted the
// whole x[] to scratch (WRITE_SIZE 177K, VGPR 84). Every x[] access in this
// kernel is now compile-time-constant-indexed.
// ---------------------------------------------------------------------------
__global__ __launch_bounds__(256, 3) void chunk_pre(const bf16* __restrict__ qkv,
                                                    const float* __restrict__ beta,
                                                    const float* __restrict__ g,
                                                    bf16* __restrict__ Wws,
                                                    bf16* __restrict__ U0ws,
                                                    float* __restrict__ lgws,
                                                    bf16* __restrict__ McT,
                                                    bf16* __restrict__ Bc) {
  __shared__ short Ksm[64][72];   // aliased: TloB (ph5), Ucr (ph6-7)
  __shared__ short Vsm[64][72];   // aliased: XB (ph4b-5), U0T (ph9-10)
  __shared__ float Tsm[64][64];   // aliased: WT (ph9-10)
  __shared__ short KpT[64][72];   // K'^T rows [k][t]
  __shared__ float lgs[64];
  __shared__ float bts[64];
  __shared__ float belg[64];

  // aliases (live ranges disjoint; barriers separate read/write phases)
  short (*XB)[36]   = (short (*)[36]) & Vsm[0][0];   // bf16 Xu [col][u], 9216B
  short (*TloB)[40] = (short (*)[40]) & Ksm[0][0];   // bf16 T[32+m][u], 2560B
  short (*UcrB)[68] = (short (*)[68]) & Ksm[0][0];   // bf16 cross-upd [row][col], 4352B
  short (*WT)[72]   = (short (*)[72]) & Tsm[0][0];
  short (*U0T)[72]  = Vsm;

  const int blk = blockIdx.x;
  const int hb = blk & 31, c = blk >> 5;   // hb fast: qkv-row L2 reuse
  const long task = (long)hb * 64 + c;
  const int h = hb & 15, b = hb >> 4, kh = h >> 1;
  const long t0 = (long)b * S_ + (long)c * CS_;
  const int tid = threadIdx.x;
  const int wv = tid >> 6, l = tid & 63;
  const int lm = l & 15, lk8 = (l >> 4) << 3;
  const int r0 = (l >> 4) << 2, cn = l & 15;
  const int srow = tid >> 2, scol = (tid & 3) * 16;

  // ph1: stage K,V
  {
    const bf16* kp = qkv + (t0 + srow) * CDIM_ + KEYD_ + kh * 64 + scol;
    const bf16* vp = qkv + (t0 + srow) * CDIM_ + 2 * KEYD_ + h * 64 + scol;
    *(bf16x8*)&Ksm[srow][scol]     = *(const bf16x8*)(kp);
    *(bf16x8*)&Ksm[srow][scol + 8] = *(const bf16x8*)(kp + 8);
    *(bf16x8*)&Vsm[srow][scol]     = *(const bf16x8*)(vp);
    *(bf16x8*)&Vsm[srow][scol + 8] = *(const bf16x8*)(vp + 8);
  }
  if (tid < 64) {
    bts[tid] = beta[(t0 + tid) * NVH_ + h];
    lgs[tid] = g[(t0 + tid) * NVH_ + h];
  }
  __syncthreads();

  // ph2: wave-parallel inclusive prefix sum of g (wave 0)
  if (tid < 64) {
    float x = lgs[tid];
#pragma unroll
    for (int d = 1; d < 64; d <<= 1) {
      const float y = __shfl_up(x, d);
      if (tid >= d) x += y;
    }
    lgs[tid] = x;
    belg[tid] = bts[tid] * __expf(x);
  }
  __syncthreads();

  // ph3: waves 0-1 KK^T -> T; waves 2-3 K'^T build
  if (tid < 128) {
    f32x4 acc[2][4] = {};
#pragma unroll
    for (int ks = 0; ks < 2; ++ks) {
      bf16x8 bfr[4];
#pragma unroll
      for (int ni = 0; ni < 4; ++ni)
        bfr[ni] = *(const bf16x8*)&Ksm[ni * 16 + lm][lk8 + ks * 32];
#pragma unroll
      for (int mi = 0; mi < 2; ++mi) {
        bf16x8 afr = *(const bf16x8*)&Ksm[(wv * 2 + mi) * 16 + lm][lk8 + ks * 32];
#pragma unroll
        for (int ni = 0; ni < 4; ++ni)
          acc[mi][ni] = __builtin_amdgcn_mfma_f32_16x16x32_bf16(afr, bfr[ni],
                                                                acc[mi][ni], 0, 0, 0);
      }
    }
#pragma unroll
    for (int mi = 0; mi < 2; ++mi)
#pragma unroll
      for (int ni = 0; ni < 4; ++ni)
#pragma unroll
        for (int r = 0; r < 4; ++r) {
          const int t = (wv * 2 + mi) * 16 + r0 + r;
          const int i = ni * 16 + cn;
          Tsm[t][i] = (i < t) ? bts[t] * __expf(lgs[t] - lgs[i]) * acc[mi][ni][r]
                              : 0.f;
        }
  } else {
    const int idx = tid - 128;
    const int tt = idx >> 1;
    const int o2 = (idx & 1) * 32;
    const float dec = __expf(lgs[63] - lgs[tt]);
#pragma unroll 8
    for (int k = 0; k < 32; ++k)
      KpT[o2 + k][tt] = f2bsh(dec * bsh2f(Ksm[tt][o2 + k]));
  }
  __syncthreads();   // Tsm, KpT, belg ready

  // register-resident solution column (threads 0-127)
  float x[64];
  const int colW = tid & 63;
  const bool isW = tid < 64;

  // ph4a: rhs init + upper 32x32 solve (threads 0-127; waves 2-3 idle,
  // co-resident WGs fill the SIMDs at 3 WG/CU)
  if (tid < 128) {
#pragma unroll
    for (int t = 0; t < CS_; ++t)
      x[t] = isW ? belg[t] * bsh2f(Ksm[t][colW])
                 : bts[t] * bsh2f(Vsm[t][colW]);
    solve32_reg<0>(x, Tsm);
  }
  if (tid < 64) lgws[task * 64 + tid] = lgs[tid];
  __syncthreads();   // Ksm/Vsm reads done -> TloB/XB regions writable

  // ph4b: bf16 conversions (owners write XB; waves 2-3 write TloB)
  if (tid < 128) {
#pragma unroll
    for (int p = 0; p < 16; ++p) {
      short2 pk; pk.x = f2bsh(x[2 * p]); pk.y = f2bsh(x[2 * p + 1]);
      *(short2*)&XB[tid][2 * p] = pk;
    }
  } else {
    const int m = (tid - 128) >> 2, u0 = (tid & 3) * 8;
#pragma unroll
    for (int u = 0; u < 8; ++u)
      TloB[m][u0 + u] = f2bsh(Tsm[32 + m][u0 + u]);
  }
  __syncthreads();

  // ph5: rank-32 cross-update via MFMA (all 4 waves, 16 MFMAs)
  f32x4 uacc2[2][2] = {};
  {
#pragma unroll
    for (int ni2 = 0; ni2 < 2; ++ni2) {
      const int ni = wv * 2 + ni2;
      bf16x8 bfr = *(const bf16x8*)&XB[ni * 16 + lm][lk8];
#pragma unroll
      for (int mi = 0; mi < 2; ++mi) {
        bf16x8 afr = *(const bf16x8*)&TloB[mi * 16 + lm][lk8];
        uacc2[ni2][mi] = __builtin_amdgcn_mfma_f32_16x16x32_bf16(afr, bfr,
                                                                 uacc2[ni2][mi], 0, 0, 0);
      }
    }
  }
  __syncthreads();   // TloB reads done -> Ucr (same region) writable

  // ph6: scatter cross-update to owners (bf16)
#pragma unroll
  for (int ni2 = 0; ni2 < 2; ++ni2)
#pragma unroll
    for (int mi = 0; mi < 2; ++mi)
#pragma unroll
      for (int r = 0; r < 4; ++r)
        UcrB[mi * 16 + r0 + r][wv * 32 + ni2 * 16 + cn] = f2bsh(uacc2[ni2][mi][r]);
  __syncthreads();

  // ph7: subtract + lower 32x32 solve (threads 0-127)
  if (tid < 128) {
#pragma unroll
    for (int i = 0; i < 32; ++i)
      x[32 + i] -= bsh2f(UcrB[i][tid]);
    solve32_reg<32>(x, Tsm);
  }
  __syncthreads();   // Tsm reads done -> WT region writable

  // ph9: write W/U0 to global + transposed bf16 into LDS (from registers).
  // FULLY unrolled: every x[] index compile-time constant (rule #20).
  if (tid < 128) {
    bf16* dst = (isW ? Wws : U0ws) + task * 4096 + colW;
    short (*XT)[72] = isW ? WT : U0T;
#pragma unroll
    for (int t = 0; t < CS_; t += 2) {
      dst[(long)t * 64] = __float2bfloat16(x[t]);
      dst[(long)(t + 1) * 64] = __float2bfloat16(x[t + 1]);
      short2 pk; pk.x = f2bsh(x[t]); pk.y = f2bsh(x[t + 1]);
      *(short2*)&XT[colW][t] = pk;
    }
  }
  __syncthreads();   // WT/U0T ready

  // ph10: McT = -(K'^T)(W^T)^T : C[m=k'][n=k] = sum_t KpT[k'][t] WT[k][t]
  {
    f32x4 macc[4] = {};
#pragma unroll
    for (int ks = 0; ks < 2; ++ks) {
      bf16x8 afr = *(const bf16x8*)&KpT[wv * 16 + lm][lk8 + ks * 32];
#pragma unroll
      for (int ni = 0; ni < 4; ++ni) {
        bf16x8 bfr = *(const bf16x8*)&WT[ni * 16 + lm][lk8 + ks * 32];
        macc[ni] = __builtin_amdgcn_mfma_f32_16x16x32_bf16(afr, bfr, macc[ni], 0, 0, 0);
      }
    }
#pragma unroll
    for (int ni = 0; ni < 4; ++ni)
#pragma unroll
      for (int r = 0; r < 4; ++r)
        McT[task * 4096 + (wv * 16 + r0 + r) * 64 + ni * 16 + cn] =
            __float2bfloat16(-macc[ni][r]);
  }
  // Bc : C[m=v][n=k'] = sum_t U0T[v][t] KpT[k'][t]
  {
    f32x4 bacc[4] = {};
#pragma unroll
    for (int ks = 0; ks < 2; ++ks) {
      bf16x8 afr = *(const bf16x8*)&U0T[wv * 16 + lm][lk8 + ks * 32];
#pragma unroll
      for (int ni = 0; ni < 4; ++ni) {
        bf16x8 bfr = *(const bf16x8*)&KpT[ni * 16 + lm][lk8 + ks * 32];
        bacc[ni] = __builtin_amdgcn_mfma_f32_16x16x32_bf16(afr, bfr, bacc[ni], 0, 0, 0);
      }
    }
#pragma unroll
    for (int ni = 0; ni < 4; ++ni)
#pragma unroll
      for (int r = 0; r < 4; ++r)
        Bc[task * 4096 + (wv * 16 + r0 + r) * 64 + ni * 16 + cn] =
            __float2bfloat16(bacc[ni][r]);
  }
}

// ---------------------------------------------------------------------------
// chunk_state (r6-validated): serial recurrence, 4 chunks per barrier-group,
// T14 async split (regs->LDS write-late, loads issued 2 groups ahead).
// ---------------------------------------------------------------------------
__global__ __launch_bounds__(256) void chunk_state(const bf16* __restrict__ McT,
                                                   const bf16* __restrict__ Bc,
                                                   const float* __restrict__ lgws,
                                                   bf16* __restrict__ Sb) {
  __shared__ short Msm[2][4][64][72];
  __shared__ short Bsm[2][4][64][72];
  __shared__ short Ssm[64][72];   // bf16 state rows [v][k] (wave-private bands)
  __shared__ float lgsm[2][4];

  const int hb = blockIdx.x;      // b*16+h
  const int tid = threadIdx.x, wv = tid >> 6, l = tid & 63;
  const int lm = l & 15, lk8 = (l >> 4) << 3;
  const int r0 = (l >> 4) << 2, cn = l & 15;
  const int srow = tid >> 2, scol = (tid & 3) * 16;

  for (int i = tid; i < 64 * 72; i += 256) ((short*)Ssm)[i] = 0;
  f32x4 Sreg[4] = {};   // fp32 master: S[v = wv*16+r0+r][k = ni*16+cn]

  // next-group staging registers (4 chunks x (M,B) x 2 bf16x8 = 64 VGPRs)
  bf16x8 mr0[4], mr1[4], br0[4], br1[4];
  float lgn0, lgn1, lgn2, lgn3;

  auto gload = [&](int g) {   // issue global loads for group g into regs
#pragma unroll
    for (int cc = 0; cc < 4; ++cc) {
      const long tt = (long)hb * 64 + g * 4 + cc;
      const bf16* mp = McT + tt * 4096 + srow * 64 + scol;
      const bf16* bp = Bc + tt * 4096 + srow * 64 + scol;
      mr0[cc] = *(const bf16x8*)(mp);
      mr1[cc] = *(const bf16x8*)(mp + 8);
      br0[cc] = *(const bf16x8*)(bp);
      br1[cc] = *(const bf16x8*)(bp + 8);
    }
    const long tb = (long)hb * 64 + g * 4;
    lgn0 = lgws[(tb + 0) * 64 + 63];
    lgn1 = lgws[(tb + 1) * 64 + 63];
    lgn2 = lgws[(tb + 2) * 64 + 63];
    lgn3 = lgws[(tb + 3) * 64 + 63];
  };
  auto lwrite = [&](int g) {  // regs -> LDS buffer g&1
    const int bu = g & 1;
#pragma unroll
    for (int cc = 0; cc < 4; ++cc) {
      *(bf16x8*)&Msm[bu][cc][srow][scol]     = mr0[cc];
      *(bf16x8*)&Msm[bu][cc][srow][scol + 8] = mr1[cc];
      *(bf16x8*)&Bsm[bu][cc][srow][scol]     = br0[cc];
      *(bf16x8*)&Bsm[bu][cc][srow][scol + 8] = br1[cc];
    }
    if (tid == 0) {
      lgsm[bu][0] = lgn0; lgsm[bu][1] = lgn1;
      lgsm[bu][2] = lgn2; lgsm[bu][3] = lgn3;
    }
  };

  gload(0);
  lwrite(0);
  gload(1);
  __syncthreads();   // buffer 0 ready; group-1 loads drained (prologue cost)

  for (int g = 0; g < 16; ++g) {
    const int bu = g & 1;
    if (g + 1 < 16) lwrite(g + 1);   // regs (drained at prev barrier) -> LDS
    if (g + 2 < 16) gload(g + 2);    // issue early; hidden under 4-chunk compute
#pragma unroll
    for (int cc = 0; cc < 4; ++cc) {
      const int c = g * 4 + cc;
      // boundary state S_c (pre-update) -> global; off critical path
      {
        bf16* sp = Sb + ((long)hb * 64 + c) * 4096;
#pragma unroll
        for (int ni = 0; ni < 4; ++ni)
#pragma unroll
          for (int r = 0; r < 4; ++r)
            sp[(wv * 16 + r0 + r) * 64 + ni * 16 + cn] = __float2bfloat16(Sreg[ni][r]);
      }
      bf16x8 sfr0 = *(const bf16x8*)&Ssm[wv * 16 + lm][lk8];
      bf16x8 sfr1 = *(const bf16x8*)&Ssm[wv * 16 + lm][lk8 + 32];
      f32x4 kacc[4] = {};
#pragma unroll
      for (int ni = 0; ni < 4; ++ni) {
        bf16x8 b0 = *(const bf16x8*)&Msm[bu][cc][ni * 16 + lm][lk8];
        kacc[ni] = __builtin_amdgcn_mfma_f32_16x16x32_bf16(sfr0, b0, kacc[ni], 0, 0, 0);
        bf16x8 b1 = *(const bf16x8*)&Msm[bu][cc][ni * 16 + lm][lk8 + 32];
        kacc[ni] = __builtin_amdgcn_mfma_f32_16x16x32_bf16(sfr1, b1, kacc[ni], 0, 0, 0);
      }
      const float eend = __expf(lgsm[bu][cc]);
#pragma unroll
      for (int ni = 0; ni < 4; ++ni)
#pragma unroll
        for (int r = 0; r < 4; ++r) {
          const float bv = bsh2f(Bsm[bu][cc][wv * 16 + r0 + r][ni * 16 + cn]);
          Sreg[ni][r] = eend * Sreg[ni][r] + kacc[ni][r] + bv;
          Ssm[wv * 16 + r0 + r][ni * 16 + cn] = f2bsh(Sreg[ni][r]);
        }
    }
    __syncthreads();   // group g reads done; g+1 LDS writes + g+2 loads drained
  }
}

// ---------------------------------------------------------------------------
// chunk_out (r2-validated): fully parallel over 2048 (b,h,chunk) tasks.
//   A[t,i]  = (q_t.k_i) * exp(lg_t - lg_i), i<=t
//   Dt[v,t] = U0[t,v] - (S0v . W^T)[v,t]
//   O[t,v]  = (e^{lg} q)_t . S0v  +  A . Dt
// ---------------------------------------------------------------------------
__global__ __launch_bounds__(256) void chunk_out(const bf16* __restrict__ qkv,
                                                 const bf16* __restrict__ Wws,
                                                 const bf16* __restrict__ U0ws,
                                                 const float* __restrict__ lgws,
                                                 const bf16* __restrict__ Sb,
                                                 float* __restrict__ o) {
  __shared__ short Qsm[64][72];   // q rows (later scaled in place by exp(lg_t))
  __shared__ short Ksm[64][72];   // k rows
  __shared__ short Wsm[64][72];   // W rows [t][dk]
  __shared__ short Usm[64][72];   // U0 rows [t][v]
  __shared__ short Amm[64][72];   // A rows [t][i]
  __shared__ short Dsm[64][72];   // Dt rows [v][t] (wave-private 16-row bands)
  __shared__ float lgs[64];

  const int blk = blockIdx.x;
  const int hb = blk & 31, c = blk >> 5;      // hb fast: qkv-row L2 reuse
  const long task = (long)hb * 64 + c;
  const int h = hb & 15, b = hb >> 4, kh = h >> 1;
  const long sb = (long)b * S_ + (long)c * CS_;
  const int tid = threadIdx.x, wv = tid >> 6, l = tid & 63;
  const int lm = l & 15, lk8 = (l >> 4) << 3;
  const int r0 = (l >> 4) << 2, cn = l & 15;
  const int srow = tid >> 2, scol = (tid & 3) * 16;

  // S0 fragments straight from global (L2-resident after chunk_state).
  const bf16* sp = Sb + task * 4096 + (wv * 16 + lm) * 64 + lk8;
  bf16x8 sfr0 = *(const bf16x8*)(sp);
  bf16x8 sfr1 = *(const bf16x8*)(sp + 32);

  {
    const bf16* qp = qkv + (sb + srow) * CDIM_ + kh * 64 + scol;
    const bf16* kp = qkv + (sb + srow) * CDIM_ + KEYD_ + kh * 64 + scol;
    const bf16* wp = Wws + task * 4096 + srow * 64 + scol;
    const bf16* up = U0ws + task * 4096 + srow * 64 + scol;
    *(bf16x8*)&Qsm[srow][scol]     = *(const bf16x8*)(qp);
    *(bf16x8*)&Qsm[srow][scol + 8] = *(const bf16x8*)(qp + 8);
    *(bf16x8*)&Ksm[srow][scol]     = *(const bf16x8*)(kp);
    *(bf16x8*)&Ksm[srow][scol + 8] = *(const bf16x8*)(kp + 8);
    *(bf16x8*)&Wsm[srow][scol]     = *(const bf16x8*)(wp);
    *(bf16x8*)&Wsm[srow][scol + 8] = *(const bf16x8*)(wp + 8);
    *(bf16x8*)&Usm[srow][scol]     = *(const bf16x8*)(up);
    *(bf16x8*)&Usm[srow][scol + 8] = *(const bf16x8*)(up + 8);
    if (tid < 64) lgs[tid] = lgws[task * 64 + tid];
  }
  __syncthreads();

  // A matrix: wave computes its 16 t-rows x all i.
  {
    f32x4 aacc[4] = {};
#pragma unroll
    for (int ks = 0; ks < 2; ++ks) {
      bf16x8 qa = *(const bf16x8*)&Qsm[wv * 16 + lm][lk8 + ks * 32];
#pragma unroll
      for (int ni = 0; ni < 4; ++ni) {
        bf16x8 kb = *(const bf16x8*)&Ksm[ni * 16 + lm][lk8 + ks * 32];
        aacc[ni] = __builtin_amdgcn_mfma_f32_16x16x32_bf16(qa, kb, aacc[ni], 0, 0, 0);
      }
    }
#pragma unroll
    for (int ni = 0; ni < 4; ++ni)
#pragma unroll
      for (int r = 0; r < 4; ++r) {
        const int t = wv * 16 + r0 + r, i = ni * 16 + cn;
        Amm[t][i] = f2bsh((i <= t) ? aacc[ni][r] * __expf(lgs[t] - lgs[i]) : 0.f);
      }
  }
  __syncthreads();  // all A-reads of Qsm done; now safe to scale Q in place

  {
    const float sc = __expf(lgs[srow]);       // Lambda_t
#pragma unroll
    for (int j = 0; j < 16; ++j)
      Qsm[srow][scol + j] = f2bsh(sc * bsh2f(Qsm[srow][scol + j]));
  }
  __syncthreads();

  // M1: Dt[v,t] = U0[t,v] - sum_k S0v[v,k] W[t,k]
  {
    f32x4 dacc[4] = {};
#pragma unroll
    for (int ni = 0; ni < 4; ++ni) {
      bf16x8 w0 = *(const bf16x8*)&Wsm[ni * 16 + lm][lk8];
      dacc[ni] = __builtin_amdgcn_mfma_f32_16x16x32_bf16(sfr0, w0, dacc[ni], 0, 0, 0);
      bf16x8 w1 = *(const bf16x8*)&Wsm[ni * 16 + lm][lk8 + 32];
      dacc[ni] = __builtin_amdgcn_mfma_f32_16x16x32_bf16(sfr1, w1, dacc[ni], 0, 0, 0);
    }
#pragma unroll
    for (int ni = 0; ni < 4; ++ni)
#pragma unroll
      for (int r = 0; r < 4; ++r) {
        const int t = ni * 16 + cn, v = r0 + r;
        Dsm[wv * 16 + v][t] = f2bsh(bsh2f(Usm[t][wv * 16 + v]) - dacc[ni][r]);
      }
  }
  // wave-private Dsm: in-wave ds ordering + compiler lgkmcnt suffice (no barrier)
  bf16x8 dfr0 = *(const bf16x8*)&Dsm[wv * 16 + lm][lk8];
  bf16x8 dfr1 = *(const bf16x8*)&Dsm[wv * 16 + lm][lk8 + 32];

  // M2+M3: O[t, v16] = LambdaQ . S0v + A . Dt
  {
    f32x4 oacc[4] = {};
#pragma unroll
    for (int mi = 0; mi < 4; ++mi) {
      bf16x8 q0 = *(const bf16x8*)&Qsm[mi * 16 + lm][lk8];
      oacc[mi] = __builtin_amdgcn_mfma_f32_16x16x32_bf16(q0, sfr0, oacc[mi], 0, 0, 0);
      bf16x8 q1 = *(const bf16x8*)&Qsm[mi * 16 + lm][lk8 + 32];
      oacc[mi] = __builtin_amdgcn_mfma_f32_16x16x32_bf16(q1, sfr1, oacc[mi], 0, 0, 0);
    }
#pragma unroll
    for (int mi = 0; mi < 4; ++mi) {
      bf16x8 a0 = *(const bf16x8*)&Amm[mi * 16 + lm][lk8];
      oacc[mi] = __builtin_amdgcn_mfma_f32_16x16x32_bf16(a0, dfr0, oacc[mi], 0, 0, 0);
      bf16x8 a1 = *(const bf16x8*)&Amm[mi * 16 + lm][lk8 + 32];
      oacc[mi] = __builtin_amdgcn_mfma_f32_16x16x32_bf16(a1, dfr1, oacc[mi], 0, 0, 0);
    }
#pragma unroll
    for (int mi = 0; mi < 4; ++mi)
#pragma unroll
      for (int r = 0; r < 4; ++r) {
        const int t = mi * 16 + r0 + r;
        o[(sb + t) * VALD_ + h * 64 + wv * 16 + cn] = oacc[mi][r];
      }
  }
}

// ---------------------------------------------------------------------------
// gnorm3 (r5-validated): h = o*silu(z); rmsnorm; *w -> bf16 hn. Vectorized.
// ---------------------------------------------------------------------------
__global__ __launch_bounds__(256) void gnorm3(const float* __restrict__ o,
                                              const float* __restrict__ z,
                                              const float* __restrict__ nw,
                                              bf16* __restrict__ hn) {
  const long idx = (long)blockIdx.x * 256 + threadIdx.x;  // M*16
  const float* op = o + idx * 64;
  const float* zp = z + idx * 64;
  float4 hv[16];
  float ss = 0.f;
#pragma unroll
  for (int i = 0; i < 16; ++i) {
    const float4 ov = *(const float4*)(op + i * 4);
    const float4 zv = *(const float4*)(zp + i * 4);
    float4 h;
    h.x = ov.x * (zv.x / (1.f + __expf(-zv.x)));
    h.y = ov.y * (zv.y / (1.f + __expf(-zv.y)));
    h.z = ov.z * (zv.z / (1.f + __expf(-zv.z)));
    h.w = ov.w * (zv.w / (1.f + __expf(-zv.w)));
    hv[i] = h;
    ss = fmaf(h.x, h.x, ss); ss = fmaf(h.y, h.y, ss);
    ss = fmaf(h.z, h.z, ss); ss = fmaf(h.w, h.w, ss);
  }
  const float r = rsqrtf(ss * (1.f / 64.f) + 1e-6f);
#pragma unroll
  for (int i = 0; i < 16; i += 2) {
    const float4 w0 = *(const float4*)(nw + i * 4);
    const float4 w1 = *(const float4*)(nw + i * 4 + 4);
    bf16x8 pk;
    pk[0] = f2bsh(hv[i].x * r * w0.x);     pk[1] = f2bsh(hv[i].y * r * w0.y);
    pk[2] = f2bsh(hv[i].z * r * w0.z);     pk[3] = f2bsh(hv[i].w * r * w0.w);
    pk[4] = f2bsh(hv[i + 1].x * r * w1.x); pk[5] = f2bsh(hv[i + 1].y * r * w1.y);
    pk[6] = f2bsh(hv[i + 1].z * r * w1.z); pk[7] = f2bsh(hv[i + 1].w * r * w1.w);
    *(bf16x8*)((uint16_t*)hn + idx * 64 + i * 4) = pk;
  }
}

// ---------------------------------------------------------------------------
extern "C" void kernel_launch(void* const* d_in, const int* in_sizes, int n_in,
                              void* d_out, int out_size, void* d_ws, size_t ws_size,
                              hipStream_t stream) {
  float* out = (float*)d_out;   // fp32 output (r8-confirmed)
  const int M = B_ * S_;        // 8192

  // input mapping (dict order confirmed; size-based fallback kept)
  int ih, iqkv, icw, iz, ib, ia, idtb, ialog, inw, iout;
  if (n_in >= 10 && in_sizes[0] == 8388608) {
    ih = 0; iqkv = 1; icw = 2; iz = 3; ib = 4; ia = 5;
    idtb = 6; ialog = 7; inw = 8; iout = 9;
  } else {
    ih = iqkv = icw = iz = ib = ia = idtb = ialog = inw = iout = -1;
    for (int i = 0; i < n_in; ++i) {
      switch (in_sizes[i]) {
        case 8388608: ih = i; break;
        case 2097152: iqkv = i; break;
        case 8192:    icw = i; break;
        case 64:      inw = i; break;
        case 1048576: if (iz < 0) iz = i; else iout = i; break;
        case 16384:   if (ib < 0) ib = i; else ia = i; break;
        case 16:      if (idtb < 0) idtb = i; else ialog = i; break;
        default: break;
      }
    }
  }
  const float* hs   = (const float*)d_in[ih];
  const float* Wqkv = (const float*)d_in[iqkv];
  const float* cw   = (const float*)d_in[icw];
  const float* Wz   = (const float*)d_in[iz];
  const float* Wb   = (const float*)d_in[ib];
  const float* Wa   = (const float*)d_in[ia];
  const float* dtb  = (const float*)d_in[idtb];
  const float* Alog = (const float*)d_in[ialog];
  const float* nwv  = (const float*)d_in[inw];
  const float* Wout = (const float*)d_in[iout];

  // workspace (~122 MiB): r2 layout; Mc/Bc alias region1 (mixed dead after
  // conv; of not written until chunk_out).
  char* p = (char*)d_ws;
  bf16*  mixed = (bf16*)p;                                 // region1: 32 MiB
  float* of    = (float*)p;                                //   of aliases mixed
  bf16*  McTw  = (bf16*)p;                                 //   McT: first 16 MiB
  bf16*  Bcw   = (bf16*)(p + (size_t)2048 * 4096 * 2);     //   Bc: second 16 MiB
  p += (size_t)M * CDIM_ * 2;
  bf16*  hs_b  = (bf16*)p;                                 // region2 (16 MiB; dead after z-gemm)
  bf16*  qkvb  = (bf16*)p;                                 //   full region2
  bf16*  hn    = (bf16*)p; p += (size_t)M * CDIM_ * 2;     //   hn aliases qkvb
  bf16*  Wqkv_b= (bf16*)p; p += (size_t)CDIM_ * H_ * 2;    // 4 MiB
  bf16*  Wz_b  = (bf16*)p; p += (size_t)H_ * H_ * 2;       // 2 MiB
  bf16*  Wout_b= (bf16*)p; p += (size_t)H_ * H_ * 2;       // 2 MiB
  float* betaf = (float*)p; p += (size_t)M * NVH_ * 4;     // 512 KiB
  float* gf    = (float*)p; p += (size_t)M * NVH_ * 4;     // 512 KiB
  bf16*  Wws   = (bf16*)p; p += (size_t)2048 * 4096 * 2;   // 16 MiB
  bf16*  U0ws  = (bf16*)p; p += (size_t)2048 * 4096 * 2;   // 16 MiB
  float* lgws  = (float*)p; p += (size_t)2048 * 64 * 4;    // 512 KiB
  bf16*  Sbw   = (bf16*)p; p += (size_t)2048 * 4096 * 2;   // 16 MiB (boundary states)
  float* zb    = out;   // z fp32 staged in d_out, consumed by gnorm3

  // 0) casts fp32 -> bf16 for MFMA operands
  {
    long n;
    n = (long)M * H_;     castf2b<<<(int)(n / 4 / 256), 256, 0, stream>>>(hs,   hs_b,   n);
    n = (long)CDIM_ * H_; castf2b<<<(int)(n / 4 / 256), 256, 0, stream>>>(Wqkv, Wqkv_b, n);
    n = (long)H_ * H_;    castf2b<<<(int)(n / 4 / 256), 256, 0, stream>>>(Wz,   Wz_b,   n);
    n = (long)H_ * H_;    castf2b<<<(int)(n / 4 / 256), 256, 0, stream>>>(Wout, Wout_b, n);
  }
  // 1) mixed = hs @ Wqkv^T  [8192 x 2048] -> bf16 (MFMA)
  gemm_bt<bf16><<<(M / 128) * (CDIM_ / 128), 256, 0, stream>>>(hs_b, Wqkv_b, mixed, M, CDIM_, H_);
  // 2) z = hs @ Wz^T  [8192 x 1024] -> fp32 in d_out (MFMA)
  gemm_bt<float><<<(M / 128) * (H_ / 128), 256, 0, stream>>>(hs_b, Wz_b, zb, M, H_, H_);
  // 3) beta, g (8 rows per block)
  proj_ba2<<<M / 8, 256, 0, stream>>>(hs, Wb, Wa, dtb, Alog, betaf, gf);
  // 4) causal depthwise conv + silu + q-scale -> bf16 (8 ch/thread vectorized)
  conv3<<<(int)(((long)M * CDIM_) / 8 / 256), 256, 0, stream>>>(mixed, cw, qkvb);
  // 5) chunked delta-rule, decoupled:
  //    a) UT-transform precompute + affine transition pieces (fused; 2048 WGs)
  chunk_pre<<<2048, 256, 0, stream>>>(qkvb, betaf, gf, Wws, U0ws, lgws, McTw, Bcw);
  //    b) serial boundary-state recurrence (32 WGs, 4 chunks/barrier-group)
  chunk_state<<<32, 256, 0, stream>>>(McTw, Bcw, lgws, Sbw);
  //    c) per-chunk outputs (parallel 2048)
  chunk_out<<<2048, 256, 0, stream>>>(qkvb, Wws, U0ws, lgws, Sbw, of);
  // 6) gated RMSNorm -> hn bf16 (vectorized)
  gnorm3<<<(M * NVH_) / 256, 256, 0, stream>>>(of, zb, nwv, hn);
  // 7) out = hn @ Wout^T -> d_out fp32 (MFMA)
  gemm_bt<float><<<(M / 128) * (H_ / 128), 256, 0, stream>>>(hn, Wout_b, out, M, H_, H_);
}

// Round 10
// 446.374 us; speedup vs baseline: 1.1404x; 1.0292x over previous
//
#include <hip/hip_runtime.h>
#include <hip/hip_bf16.h>
#include <stdint.h>

// Problem constants
#define B_    2
#define S_    4096
#define H_    1024
#define NKH_  8
#define NVH_  16
#define DK_   64
#define DV_   64
#define KEYD_ 512          // NKH*DK
#define CDIM_ 2048         // 2*KEYD + VAL_DIM
#define VALD_ 1024         // NVH*DV
#define NCHUNK_ 64         // S_/64
#define CS_   64           // chunk size

using bf16 = __hip_bfloat16;
using bf16x8 = __attribute__((ext_vector_type(8))) short;  // 8 bf16 = 4 VGPRs
using f32x4  = __attribute__((ext_vector_type(4))) float;

__device__ inline float bsh2f(short s) {
  union { ushort u; bf16 h; } c; c.u = (ushort)s; return __bfloat162float(c.h);
}
__device__ inline short f2bsh(float f) {
  union { ushort u; bf16 h; } c; c.h = __float2bfloat16(f); return (short)c.u;
}

// async global->LDS, 16B per lane; dest = uniform base + lane*16 (HW rule).
__device__ __forceinline__ void gload16(const bf16* g, short* lds) {
  __builtin_amdgcn_global_load_lds(
      (const __attribute__((address_space(1))) void*)g,
      (__attribute__((address_space(3))) void*)lds, 16, 0, 0);
}

// XCD-aware bijective block swizzle (T1; requires nwg % 8 == 0, true for all
// grids here). Consecutive post-swizzle IDs land on the SAME XCD -> shared
// operand panels stay L2-resident per XCD.
__device__ __forceinline__ int xcd_swz(int bid, int nwg) {
  return (bid & 7) * (nwg >> 3) + (bid >> 3);
}

// ---------------------------------------------------------------------------
// 32x32 fp32 forward-substitution on register-resident column x, rows
// [BASE, BASE+32). BASE is a TEMPLATE parameter so every x[] index is a
// compile-time constant after unrolling (rule #20: runtime-indexed register
// arrays go to scratch — r7/r8 regressions).
// ---------------------------------------------------------------------------
template <int BASE>
__device__ __forceinline__ void solve32_reg(float (&x)[64],
                                            const float (*T)[64]) {
#pragma unroll
  for (int jj = 0; jj < 32; jj += 8) {
    const int j = BASE + jj;
    float xs[8];
#pragma unroll
    for (int a = 0; a < 8; ++a) xs[a] = x[j + a];
#pragma unroll
    for (int a = 1; a < 8; ++a)
#pragma unroll
      for (int bb = 0; bb < a; ++bb)
        xs[a] = fmaf(-T[j + a][j + bb], xs[bb], xs[a]);
#pragma unroll
    for (int a = 1; a < 8; ++a) x[j + a] = xs[a];
#pragma unroll
    for (int t2 = jj + 8; t2 < 32; ++t2) {
      const int tt = BASE + t2;
      const float4 ta = *(const float4*)&T[tt][j];
      const float4 tb = *(const float4*)&T[tt][j + 4];
      float v = x[tt];
      v = fmaf(-ta.x, xs[0], v); v = fmaf(-ta.y, xs[1], v);
      v = fmaf(-ta.z, xs[2], v); v = fmaf(-ta.w, xs[3], v);
      v = fmaf(-tb.x, xs[4], v); v = fmaf(-tb.y, xs[5], v);
      v = fmaf(-tb.z, xs[6], v); v = fmaf(-tb.w, xs[7], v);
      x[tt] = v;
    }
  }
}

// ---------------------------------------------------------------------------
// fp32 -> bf16 cast, 4 elems/thread (n % 4 == 0). (r2-validated structure)
// ---------------------------------------------------------------------------
__global__ __launch_bounds__(256) void castf2b(const float* __restrict__ x,
                                               bf16* __restrict__ y, long n) {
  const long i = ((long)blockIdx.x * 256 + threadIdx.x) * 4;
  if (i >= n) return;
  float4 v = *(const float4*)(x + i);
  union { ushort4 u; bf16 h[4]; } o;
  o.h[0] = __float2bfloat16(v.x);
  o.h[1] = __float2bfloat16(v.y);
  o.h[2] = __float2bfloat16(v.z);
  o.h[3] = __float2bfloat16(v.w);
  *(ushort4*)(y + i) = o.u;
}

// ---------------------------------------------------------------------------
// MFMA GEMM (r4-validated): C[m,n] = sum_k A[m,k]*B[n,k]; A,B bf16;
// C bf16 or fp32. 128x128 tile, 4 waves 2x2, 4x4 of 16x16x32 MFMA, BK=32.
// Staging via global_load_lds width=16 (m97 ladder step-3).
// r10: + XCD swizzle — each XCD owns a contiguous bm-range so the B matrix
// (2-4 MB, L2-resident per XCD) stops being re-fetched (FETCH was 3.5x ideal).
// ---------------------------------------------------------------------------
template <typename OT>
__global__ __launch_bounds__(256) void gemm_bt(const bf16* __restrict__ A,
                                               const bf16* __restrict__ Bm,
                                               OT* __restrict__ C,
                                               int M, int N, int K) {
  __shared__ short Asm[128 * 32];
  __shared__ short Bsm[128 * 32];
  const int t = threadIdx.x;
  const int w = t >> 6, l = t & 63;
  const int ntn = N >> 7;
  const int bid = xcd_swz(blockIdx.x, gridDim.x);
  const int bm = bid / ntn, bn = bid % ntn;
  const int m0 = bm << 7, n0 = bn << 7;
  const int wm = (w >> 1) << 6, wn = (w & 1) << 6;

  f32x4 acc[4][4] = {};

  const int grow = l >> 2;            // 0..15 within slab
  const int gc8 = (l & 3) << 3;       // 0,8,16,24
  const bf16* Agl = A + (long)m0 * K + gc8;
  const bf16* Bgl = Bm + (long)n0 * K + gc8;

  const int lm = l & 15;
  const int kk = (l >> 4) << 3;
  const short* ar0 = &Asm[(wm + lm) * 32 + kk];
  const short* br0 = &Bsm[(wn + lm) * 32 + kk];

  for (int k0 = 0; k0 < K; k0 += 32) {
    __syncthreads();   // prev-iter LDS reads done
#pragma unroll
    for (int j = 0; j < 2; ++j) {
      const int s = w * 2 + j;        // slab 0..7 (wave-uniform)
      gload16(Agl + (long)(s * 16 + grow) * K + k0, &Asm[s * 16 * 32]);
      gload16(Bgl + (long)(s * 16 + grow) * K + k0, &Bsm[s * 16 * 32]);
    }
    __syncthreads();   // compiler drains vmcnt before barrier -> LDS ready
    bf16x8 af[4], bfr[4];
#pragma unroll
    for (int mi = 0; mi < 4; ++mi) af[mi] = *(const bf16x8*)(ar0 + mi * 16 * 32);
#pragma unroll
    for (int ni = 0; ni < 4; ++ni) bfr[ni] = *(const bf16x8*)(br0 + ni * 16 * 32);
#pragma unroll
    for (int mi = 0; mi < 4; ++mi)
#pragma unroll
      for (int ni = 0; ni < 4; ++ni)
        acc[mi][ni] = __builtin_amdgcn_mfma_f32_16x16x32_bf16(af[mi], bfr[ni],
                                                              acc[mi][ni], 0, 0, 0);
  }

  // C/D layout: col = l&15, row = (l>>4)*4 + reg
  const int r0 = (l >> 4) << 2;
  const int cn = l & 15;
#pragma unroll
  for (int mi = 0; mi < 4; ++mi)
#pragma unroll
    for (int ni = 0; ni < 4; ++ni) {
      long base = (long)(m0 + wm + mi * 16 + r0) * N + (n0 + wn + ni * 16 + cn);
#pragma unroll
      for (int r = 0; r < 4; ++r) {
        if constexpr (sizeof(OT) == 2)
          C[base + (long)r * N] = __float2bfloat16(acc[mi][ni][r]);
        else
          C[base + (long)r * N] = acc[mi][ni][r];
      }
    }
}

// ---------------------------------------------------------------------------
// conv3 (r5-validated): causal depthwise k=4 conv + silu + q-scale, 8 ch/thr.
// ---------------------------------------------------------------------------
__global__ __launch_bounds__(256) void conv3(const bf16* __restrict__ mixed,
                                             const float* __restrict__ cw,
                                             bf16* __restrict__ qkv) {
  const long idx = (long)blockIdx.x * 256 + threadIdx.x;  // over M*256 groups
  const int c0 = (int)(idx & 255) << 3;                   // channel group base
  const long row = idx >> 8;
  const int s = (int)(row & (S_ - 1));

  bf16x8 mv[4];
#pragma unroll
  for (int j = 0; j < 4; ++j) {
    if (s - 3 + j >= 0)
      mv[j] = *(const bf16x8*)(mixed + (row + j - 3) * CDIM_ + c0);
    else
      mv[j] = (bf16x8){0, 0, 0, 0, 0, 0, 0, 0};
  }

  const float qs = (c0 < KEYD_) ? 0.125f : 1.f;
  union { ushort4 u4[2]; short h[8]; } o;
#pragma unroll
  for (int e = 0; e < 8; ++e) {
    const float4 w = *(const float4*)(cw + (c0 + e) * 4);
    float acc = 0.f;
    acc = fmaf(w.x, bsh2f(mv[0][e]), acc);
    acc = fmaf(w.y, bsh2f(mv[1][e]), acc);
    acc = fmaf(w.z, bsh2f(mv[2][e]), acc);
    acc = fmaf(w.w, bsh2f(mv[3][e]), acc);
    const float y = qs * (acc / (1.f + __expf(-acc)));    // silu (+ q-scale)
    o.h[e] = f2bsh(y);
  }
  *(bf16x8*)((uint16_t*)qkv + row * CDIM_ + c0) = *(bf16x8*)&o.h[0];
}

// ---------------------------------------------------------------------------
// proj_ba2 (r3-validated): 8 rows per block; W traffic cut 8x.
// ---------------------------------------------------------------------------
__global__ __launch_bounds__(256) void proj_ba2(const float* __restrict__ hs,
                                                const float* __restrict__ Wb,
                                                const float* __restrict__ Wa,
                                                const float* __restrict__ dtb,
                                                const float* __restrict__ Alog,
                                                float* __restrict__ beta,
                                                float* __restrict__ g) {
  __shared__ float4 hrow[8][257];   // +1 float4 pad
  const long row0 = (long)blockIdx.x * 8;
  const int tid = threadIdx.x;
  for (int i = tid; i < 2048; i += 256) {
    const int r = i >> 8, c4 = i & 255;
    hrow[r][c4] = *(const float4*)(hs + (row0 + r) * H_ + (long)c4 * 4);
  }
  __syncthreads();
  const int j = tid >> 3, r = tid & 7;
  const float4* Wp = (const float4*)(j < 16 ? Wb + (long)j * H_
                                            : Wa + (long)(j - 16) * H_);
  float4 a4 = {0.f, 0.f, 0.f, 0.f};
#pragma unroll 4
  for (int i = 0; i < 256; ++i) {
    const float4 w = Wp[i];
    const float4 hv = hrow[r][i];
    a4.x = fmaf(w.x, hv.x, a4.x);
    a4.y = fmaf(w.y, hv.y, a4.y);
    a4.z = fmaf(w.z, hv.z, a4.z);
    a4.w = fmaf(w.w, hv.w, a4.w);
  }
  const float acc = (a4.x + a4.y) + (a4.z + a4.w);
  const long row = row0 + r;
  if (j < 16) {
    beta[row * NVH_ + j] = 1.f / (1.f + __expf(-acc));
  } else {
    const int hh = j - 16;
    const float x = acc + dtb[hh];
    const float sp = (x > 20.f) ? x : log1pf(__expf(x));
    g[row * NVH_ + hh] = -__expf(Alog[hh]) * sp;
  }
}

// ---------------------------------------------------------------------------
// chunk_pre (r9-validated + r10 XCD swizzle): per (b,h,chunk) task:
//   lg = cumsum(g); T[t,i] = beta_t e^{lg_t-lg_i}(k_t.k_i), i<t
//   solve (I+T)X = [diag(beta e^lg)K | diag(beta)V] -> W,U0
//   K' = e^{lg63-lg_t} k; McT = -K'^T W; Bc = U0^T K' (MFMA)
// Register-resident solve; every x[] access compile-time-constant-indexed.
// ---------------------------------------------------------------------------
__global__ __launch_bounds__(256, 3) void chunk_pre(const bf16* __restrict__ qkv,
                                                    const float* __restrict__ beta,
                                                    const float* __restrict__ g,
                                                    bf16* __restrict__ Wws,
                                                    bf16* __restrict__ U0ws,
                                                    float* __restrict__ lgws,
                                                    bf16* __restrict__ McT,
                                                    bf16* __restrict__ Bc) {
  __shared__ short Ksm[64][72];   // aliased: TloB (ph5), Ucr (ph6-7)
  __shared__ short Vsm[64][72];   // aliased: XB (ph4b-5), U0T (ph9-10)
  __shared__ float Tsm[64][64];   // aliased: WT (ph9-10)
  __shared__ short KpT[64][72];   // K'^T rows [k][t]
  __shared__ float lgs[64];
  __shared__ float bts[64];
  __shared__ float belg[64];

  // aliases (live ranges disjoint; barriers separate read/write phases)
  short (*XB)[36]   = (short (*)[36]) & Vsm[0][0];   // bf16 Xu [col][u], 9216B
  short (*TloB)[40] = (short (*)[40]) & Ksm[0][0];   // bf16 T[32+m][u], 2560B
  short (*UcrB)[68] = (short (*)[68]) & Ksm[0][0];   // bf16 cross-upd [row][col], 4352B
  short (*WT)[72]   = (short (*)[72]) & Tsm[0][0];
  short (*U0T)[72]  = Vsm;

  const int blk = xcd_swz(blockIdx.x, 2048);   // XCD owns contiguous chunk range
  const int hb = blk & 31, c = blk >> 5;       // hb fast: qkv-row L2 reuse
  const long task = (long)hb * 64 + c;
  const int h = hb & 15, b = hb >> 4, kh = h >> 1;
  const long t0 = (long)b * S_ + (long)c * CS_;
  const int tid = threadIdx.x;
  const int wv = tid >> 6, l = tid & 63;
  const int lm = l & 15, lk8 = (l >> 4) << 3;
  const int r0 = (l >> 4) << 2, cn = l & 15;
  const int srow = tid >> 2, scol = (tid & 3) * 16;

  // ph1: stage K,V
  {
    const bf16* kp = qkv + (t0 + srow) * CDIM_ + KEYD_ + kh * 64 + scol;
    const bf16* vp = qkv + (t0 + srow) * CDIM_ + 2 * KEYD_ + h * 64 + scol;
    *(bf16x8*)&Ksm[srow][scol]     = *(const bf16x8*)(kp);
    *(bf16x8*)&Ksm[srow][scol + 8] = *(const bf16x8*)(kp + 8);
    *(bf16x8*)&Vsm[srow][scol]     = *(const bf16x8*)(vp);
    *(bf16x8*)&Vsm[srow][scol + 8] = *(const bf16x8*)(vp + 8);
  }
  if (tid < 64) {
    bts[tid] = beta[(t0 + tid) * NVH_ + h];
    lgs[tid] = g[(t0 + tid) * NVH_ + h];
  }
  __syncthreads();

  // ph2: wave-parallel inclusive prefix sum of g (wave 0)
  if (tid < 64) {
    float x = lgs[tid];
#pragma unroll
    for (int d = 1; d < 64; d <<= 1) {
      const float y = __shfl_up(x, d);
      if (tid >= d) x += y;
    }
    lgs[tid] = x;
    belg[tid] = bts[tid] * __expf(x);
  }
  __syncthreads();

  // ph3: waves 0-1 KK^T -> T; waves 2-3 K'^T build
  if (tid < 128) {
    f32x4 acc[2][4] = {};
#pragma unroll
    for (int ks = 0; ks < 2; ++ks) {
      bf16x8 bfr[4];
#pragma unroll
      for (int ni = 0; ni < 4; ++ni)
        bfr[ni] = *(const bf16x8*)&Ksm[ni * 16 + lm][lk8 + ks * 32];
#pragma unroll
      for (int mi = 0; mi < 2; ++mi) {
        bf16x8 afr = *(const bf16x8*)&Ksm[(wv * 2 + mi) * 16 + lm][lk8 + ks * 32];
#pragma unroll
        for (int ni = 0; ni < 4; ++ni)
          acc[mi][ni] = __builtin_amdgcn_mfma_f32_16x16x32_bf16(afr, bfr[ni],
                                                                acc[mi][ni], 0, 0, 0);
      }
    }
#pragma unroll
    for (int mi = 0; mi < 2; ++mi)
#pragma unroll
      for (int ni = 0; ni < 4; ++ni)
#pragma unroll
        for (int r = 0; r < 4; ++r) {
          const int t = (wv * 2 + mi) * 16 + r0 + r;
          const int i = ni * 16 + cn;
          Tsm[t][i] = (i < t) ? bts[t] * __expf(lgs[t] - lgs[i]) * acc[mi][ni][r]
                              : 0.f;
        }
  } else {
    const int idx = tid - 128;
    const int tt = idx >> 1;
    const int o2 = (idx & 1) * 32;
    const float dec = __expf(lgs[63] - lgs[tt]);
#pragma unroll 8
    for (int k = 0; k < 32; ++k)
      KpT[o2 + k][tt] = f2bsh(dec * bsh2f(Ksm[tt][o2 + k]));
  }
  __syncthreads();   // Tsm, KpT, belg ready

  // register-resident solution column (threads 0-127)
  float x[64];
  const int colW = tid & 63;
  const bool isW = tid < 64;

  // ph4a: rhs init + upper 32x32 solve (threads 0-127; waves 2-3 idle,
  // co-resident WGs fill the SIMDs at 3 WG/CU)
  if (tid < 128) {
#pragma unroll
    for (int t = 0; t < CS_; ++t)
      x[t] = isW ? belg[t] * bsh2f(Ksm[t][colW])
                 : bts[t] * bsh2f(Vsm[t][colW]);
    solve32_reg<0>(x, Tsm);
  }
  if (tid < 64) lgws[task * 64 + tid] = lgs[tid];
  __syncthreads();   // Ksm/Vsm reads done -> TloB/XB regions writable

  // ph4b: bf16 conversions (owners write XB; waves 2-3 write TloB)
  if (tid < 128) {
#pragma unroll
    for (int p = 0; p < 16; ++p) {
      short2 pk; pk.x = f2bsh(x[2 * p]); pk.y = f2bsh(x[2 * p + 1]);
      *(short2*)&XB[tid][2 * p] = pk;
    }
  } else {
    const int m = (tid - 128) >> 2, u0 = (tid & 3) * 8;
#pragma unroll
    for (int u = 0; u < 8; ++u)
      TloB[m][u0 + u] = f2bsh(Tsm[32 + m][u0 + u]);
  }
  __syncthreads();

  // ph5: rank-32 cross-update via MFMA (all 4 waves, 16 MFMAs)
  f32x4 uacc2[2][2] = {};
  {
#pragma unroll
    for (int ni2 = 0; ni2 < 2; ++ni2) {
      const int ni = wv * 2 + ni2;
      bf16x8 bfr = *(const bf16x8*)&XB[ni * 16 + lm][lk8];
#pragma unroll
      for (int mi = 0; mi < 2; ++mi) {
        bf16x8 afr = *(const bf16x8*)&TloB[mi * 16 + lm][lk8];
        uacc2[ni2][mi] = __builtin_amdgcn_mfma_f32_16x16x32_bf16(afr, bfr,
                                                                 uacc2[ni2][mi], 0, 0, 0);
      }
    }
  }
  __syncthreads();   // TloB reads done -> Ucr (same region) writable

  // ph6: scatter cross-update to owners (bf16)
#pragma unroll
  for (int ni2 = 0; ni2 < 2; ++ni2)
#pragma unroll
    for (int mi = 0; mi < 2; ++mi)
#pragma unroll
      for (int r = 0; r < 4; ++r)
        UcrB[mi * 16 + r0 + r][wv * 32 + ni2 * 16 + cn] = f2bsh(uacc2[ni2][mi][r]);
  __syncthreads();

  // ph7: subtract + lower 32x32 solve (threads 0-127)
  if (tid < 128) {
#pragma unroll
    for (int i = 0; i < 32; ++i)
      x[32 + i] -= bsh2f(UcrB[i][tid]);
    solve32_reg<32>(x, Tsm);
  }
  __syncthreads();   // Tsm reads done -> WT region writable

  // ph9: write W/U0 to global + transposed bf16 into LDS (from registers).
  // FULLY unrolled: every x[] index compile-time constant (rule #20).
  if (tid < 128) {
    bf16* dst = (isW ? Wws : U0ws) + task * 4096 + colW;
    short (*XT)[72] = isW ? WT : U0T;
#pragma unroll
    for (int t = 0; t < CS_; t += 2) {
      dst[(long)t * 64] = __float2bfloat16(x[t]);
      dst[(long)(t + 1) * 64] = __float2bfloat16(x[t + 1]);
      short2 pk; pk.x = f2bsh(x[t]); pk.y = f2bsh(x[t + 1]);
      *(short2*)&XT[colW][t] = pk;
    }
  }
  __syncthreads();   // WT/U0T ready

  // ph10: McT = -(K'^T)(W^T)^T : C[m=k'][n=k] = sum_t KpT[k'][t] WT[k][t]
  {
    f32x4 macc[4] = {};
#pragma unroll
    for (int ks = 0; ks < 2; ++ks) {
      bf16x8 afr = *(const bf16x8*)&KpT[wv * 16 + lm][lk8 + ks * 32];
#pragma unroll
      for (int ni = 0; ni < 4; ++ni) {
        bf16x8 bfr = *(const bf16x8*)&WT[ni * 16 + lm][lk8 + ks * 32];
        macc[ni] = __builtin_amdgcn_mfma_f32_16x16x32_bf16(afr, bfr, macc[ni], 0, 0, 0);
      }
    }
#pragma unroll
    for (int ni = 0; ni < 4; ++ni)
#pragma unroll
      for (int r = 0; r < 4; ++r)
        McT[task * 4096 + (wv * 16 + r0 + r) * 64 + ni * 16 + cn] =
            __float2bfloat16(-macc[ni][r]);
  }
  // Bc : C[m=v][n=k'] = sum_t U0T[v][t] KpT[k'][t]
  {
    f32x4 bacc[4] = {};
#pragma unroll
    for (int ks = 0; ks < 2; ++ks) {
      bf16x8 afr = *(const bf16x8*)&U0T[wv * 16 + lm][lk8 + ks * 32];
#pragma unroll
      for (int ni = 0; ni < 4; ++ni) {
        bf16x8 bfr = *(const bf16x8*)&KpT[ni * 16 + lm][lk8 + ks * 32];
        bacc[ni] = __builtin_amdgcn_mfma_f32_16x16x32_bf16(afr, bfr, bacc[ni], 0, 0, 0);
      }
    }
#pragma unroll
    for (int ni = 0; ni < 4; ++ni)
#pragma unroll
      for (int r = 0; r < 4; ++r)
        Bc[task * 4096 + (wv * 16 + r0 + r) * 64 + ni * 16 + cn] =
            __float2bfloat16(bacc[ni][r]);
  }
}

// ---------------------------------------------------------------------------
// chunk_state (r6-validated): serial recurrence, 4 chunks per barrier-group,
// T14 async split (regs->LDS write-late, loads issued 2 groups ahead).
// ---------------------------------------------------------------------------
__global__ __launch_bounds__(256) void chunk_state(const bf16* __restrict__ McT,
                                                   const bf16* __restrict__ Bc,
                                                   const float* __restrict__ lgws,
                                                   bf16* __restrict__ Sb) {
  __shared__ short Msm[2][4][64][72];
  __shared__ short Bsm[2][4][64][72];
  __shared__ short Ssm[64][72];   // bf16 state rows [v][k] (wave-private bands)
  __shared__ float lgsm[2][4];

  const int hb = blockIdx.x;      // b*16+h
  const int tid = threadIdx.x, wv = tid >> 6, l = tid & 63;
  const int lm = l & 15, lk8 = (l >> 4) << 3;
  const int r0 = (l >> 4) << 2, cn = l & 15;
  const int srow = tid >> 2, scol = (tid & 3) * 16;

  for (int i = tid; i < 64 * 72; i += 256) ((short*)Ssm)[i] = 0;
  f32x4 Sreg[4] = {};   // fp32 master: S[v = wv*16+r0+r][k = ni*16+cn]

  // next-group staging registers (4 chunks x (M,B) x 2 bf16x8 = 64 VGPRs)
  bf16x8 mr0[4], mr1[4], br0[4], br1[4];
  float lgn0, lgn1, lgn2, lgn3;

  auto gload = [&](int g) {   // issue global loads for group g into regs
#pragma unroll
    for (int cc = 0; cc < 4; ++cc) {
      const long tt = (long)hb * 64 + g * 4 + cc;
      const bf16* mp = McT + tt * 4096 + srow * 64 + scol;
      const bf16* bp = Bc + tt * 4096 + srow * 64 + scol;
      mr0[cc] = *(const bf16x8*)(mp);
      mr1[cc] = *(const bf16x8*)(mp + 8);
      br0[cc] = *(const bf16x8*)(bp);
      br1[cc] = *(const bf16x8*)(bp + 8);
    }
    const long tb = (long)hb * 64 + g * 4;
    lgn0 = lgws[(tb + 0) * 64 + 63];
    lgn1 = lgws[(tb + 1) * 64 + 63];
    lgn2 = lgws[(tb + 2) * 64 + 63];
    lgn3 = lgws[(tb + 3) * 64 + 63];
  };
  auto lwrite = [&](int g) {  // regs -> LDS buffer g&1
    const int bu = g & 1;
#pragma unroll
    for (int cc = 0; cc < 4; ++cc) {
      *(bf16x8*)&Msm[bu][cc][srow][scol]     = mr0[cc];
      *(bf16x8*)&Msm[bu][cc][srow][scol + 8] = mr1[cc];
      *(bf16x8*)&Bsm[bu][cc][srow][scol]     = br0[cc];
      *(bf16x8*)&Bsm[bu][cc][srow][scol + 8] = br1[cc];
    }
    if (tid == 0) {
      lgsm[bu][0] = lgn0; lgsm[bu][1] = lgn1;
      lgsm[bu][2] = lgn2; lgsm[bu][3] = lgn3;
    }
  };

  gload(0);
  lwrite(0);
  gload(1);
  __syncthreads();   // buffer 0 ready; group-1 loads drained (prologue cost)

  for (int g = 0; g < 16; ++g) {
    const int bu = g & 1;
    if (g + 1 < 16) lwrite(g + 1);   // regs (drained at prev barrier) -> LDS
    if (g + 2 < 16) gload(g + 2);    // issue early; hidden under 4-chunk compute
#pragma unroll
    for (int cc = 0; cc < 4; ++cc) {
      const int c = g * 4 + cc;
      // boundary state S_c (pre-update) -> global; off critical path
      {
        bf16* sp = Sb + ((long)hb * 64 + c) * 4096;
#pragma unroll
        for (int ni = 0; ni < 4; ++ni)
#pragma unroll
          for (int r = 0; r < 4; ++r)
            sp[(wv * 16 + r0 + r) * 64 + ni * 16 + cn] = __float2bfloat16(Sreg[ni][r]);
      }
      bf16x8 sfr0 = *(const bf16x8*)&Ssm[wv * 16 + lm][lk8];
      bf16x8 sfr1 = *(const bf16x8*)&Ssm[wv * 16 + lm][lk8 + 32];
      f32x4 kacc[4] = {};
#pragma unroll
      for (int ni = 0; ni < 4; ++ni) {
        bf16x8 b0 = *(const bf16x8*)&Msm[bu][cc][ni * 16 + lm][lk8];
        kacc[ni] = __builtin_amdgcn_mfma_f32_16x16x32_bf16(sfr0, b0, kacc[ni], 0, 0, 0);
        bf16x8 b1 = *(const bf16x8*)&Msm[bu][cc][ni * 16 + lm][lk8 + 32];
        kacc[ni] = __builtin_amdgcn_mfma_f32_16x16x32_bf16(sfr1, b1, kacc[ni], 0, 0, 0);
      }
      const float eend = __expf(lgsm[bu][cc]);
#pragma unroll
      for (int ni = 0; ni < 4; ++ni)
#pragma unroll
        for (int r = 0; r < 4; ++r) {
          const float bv = bsh2f(Bsm[bu][cc][wv * 16 + r0 + r][ni * 16 + cn]);
          Sreg[ni][r] = eend * Sreg[ni][r] + kacc[ni][r] + bv;
          Ssm[wv * 16 + r0 + r][ni * 16 + cn] = f2bsh(Sreg[ni][r]);
        }
    }
    __syncthreads();   // group g reads done; g+1 LDS writes + g+2 loads drained
  }
}

// ---------------------------------------------------------------------------
// chunk_out (r2-validated + r10 XCD swizzle): fully parallel over 2048 tasks.
//   A[t,i]  = (q_t.k_i) * exp(lg_t - lg_i), i<=t
//   Dt[v,t] = U0[t,v] - (S0v . W^T)[v,t]
//   O[t,v]  = (e^{lg} q)_t . S0v  +  A . Dt
// ---------------------------------------------------------------------------
__global__ __launch_bounds__(256) void chunk_out(const bf16* __restrict__ qkv,
                                                 const bf16* __restrict__ Wws,
                                                 const bf16* __restrict__ U0ws,
                                                 const float* __restrict__ lgws,
                                                 const bf16* __restrict__ Sb,
                                                 float* __restrict__ o) {
  __shared__ short Qsm[64][72];   // q rows (later scaled in place by exp(lg_t))
  __shared__ short Ksm[64][72];   // k rows
  __shared__ short Wsm[64][72];   // W rows [t][dk]
  __shared__ short Usm[64][72];   // U0 rows [t][v]
  __shared__ short Amm[64][72];   // A rows [t][i]
  __shared__ short Dsm[64][72];   // Dt rows [v][t] (wave-private 16-row bands)
  __shared__ float lgs[64];

  const int blk = xcd_swz(blockIdx.x, 2048);   // XCD owns contiguous chunk range
  const int hb = blk & 31, c = blk >> 5;       // hb fast: qkv-row L2 reuse
  const long task = (long)hb * 64 + c;
  const int h = hb & 15, b = hb >> 4, kh = h >> 1;
  const long sb = (long)b * S_ + (long)c * CS_;
  const int tid = threadIdx.x, wv = tid >> 6, l = tid & 63;
  const int lm = l & 15, lk8 = (l >> 4) << 3;
  const int r0 = (l >> 4) << 2, cn = l & 15;
  const int srow = tid >> 2, scol = (tid & 3) * 16;

  // S0 fragments straight from global (L2-resident after chunk_state).
  const bf16* sp = Sb + task * 4096 + (wv * 16 + lm) * 64 + lk8;
  bf16x8 sfr0 = *(const bf16x8*)(sp);
  bf16x8 sfr1 = *(const bf16x8*)(sp + 32);

  {
    const bf16* qp = qkv + (sb + srow) * CDIM_ + kh * 64 + scol;
    const bf16* kp = qkv + (sb + srow) * CDIM_ + KEYD_ + kh * 64 + scol;
    const bf16* wp = Wws + task * 4096 + srow * 64 + scol;
    const bf16* up = U0ws + task * 4096 + srow * 64 + scol;
    *(bf16x8*)&Qsm[srow][scol]     = *(const bf16x8*)(qp);
    *(bf16x8*)&Qsm[srow][scol + 8] = *(const bf16x8*)(qp + 8);
    *(bf16x8*)&Ksm[srow][scol]     = *(const bf16x8*)(kp);
    *(bf16x8*)&Ksm[srow][scol + 8] = *(const bf16x8*)(kp + 8);
    *(bf16x8*)&Wsm[srow][scol]     = *(const bf16x8*)(wp);
    *(bf16x8*)&Wsm[srow][scol + 8] = *(const bf16x8*)(wp + 8);
    *(bf16x8*)&Usm[srow][scol]     = *(const bf16x8*)(up);
    *(bf16x8*)&Usm[srow][scol + 8] = *(const bf16x8*)(up + 8);
    if (tid < 64) lgs[tid] = lgws[task * 64 + tid];
  }
  __syncthreads();

  // A matrix: wave computes its 16 t-rows x all i.
  {
    f32x4 aacc[4] = {};
#pragma unroll
    for (int ks = 0; ks < 2; ++ks) {
      bf16x8 qa = *(const bf16x8*)&Qsm[wv * 16 + lm][lk8 + ks * 32];
#pragma unroll
      for (int ni = 0; ni < 4; ++ni) {
        bf16x8 kb = *(const bf16x8*)&Ksm[ni * 16 + lm][lk8 + ks * 32];
        aacc[ni] = __builtin_amdgcn_mfma_f32_16x16x32_bf16(qa, kb, aacc[ni], 0, 0, 0);
      }
    }
#pragma unroll
    for (int ni = 0; ni < 4; ++ni)
#pragma unroll
      for (int r = 0; r < 4; ++r) {
        const int t = wv * 16 + r0 + r, i = ni * 16 + cn;
        Amm[t][i] = f2bsh((i <= t) ? aacc[ni][r] * __expf(lgs[t] - lgs[i]) : 0.f);
      }
  }
  __syncthreads();  // all A-reads of Qsm done; now safe to scale Q in place

  {
    const float sc = __expf(lgs[srow]);       // Lambda_t
#pragma unroll
    for (int j = 0; j < 16; ++j)
      Qsm[srow][scol + j] = f2bsh(sc * bsh2f(Qsm[srow][scol + j]));
  }
  __syncthreads();

  // M1: Dt[v,t] = U0[t,v] - sum_k S0v[v,k] W[t,k]
  {
    f32x4 dacc[4] = {};
#pragma unroll
    for (int ni = 0; ni < 4; ++ni) {
      bf16x8 w0 = *(const bf16x8*)&Wsm[ni * 16 + lm][lk8];
      dacc[ni] = __builtin_amdgcn_mfma_f32_16x16x32_bf16(sfr0, w0, dacc[ni], 0, 0, 0);
      bf16x8 w1 = *(const bf16x8*)&Wsm[ni * 16 + lm][lk8 + 32];
      dacc[ni] = __builtin_amdgcn_mfma_f32_16x16x32_bf16(sfr1, w1, dacc[ni], 0, 0, 0);
    }
#pragma unroll
    for (int ni = 0; ni < 4; ++ni)
#pragma unroll
      for (int r = 0; r < 4; ++r) {
        const int t = ni * 16 + cn, v = r0 + r;
        Dsm[wv * 16 + v][t] = f2bsh(bsh2f(Usm[t][wv * 16 + v]) - dacc[ni][r]);
      }
  }
  // wave-private Dsm: in-wave ds ordering + compiler lgkmcnt suffice (no barrier)
  bf16x8 dfr0 = *(const bf16x8*)&Dsm[wv * 16 + lm][lk8];
  bf16x8 dfr1 = *(const bf16x8*)&Dsm[wv * 16 + lm][lk8 + 32];

  // M2+M3: O[t, v16] = LambdaQ . S0v + A . Dt
  {
    f32x4 oacc[4] = {};
#pragma unroll
    for (int mi = 0; mi < 4; ++mi) {
      bf16x8 q0 = *(const bf16x8*)&Qsm[mi * 16 + lm][lk8];
      oacc[mi] = __builtin_amdgcn_mfma_f32_16x16x32_bf16(q0, sfr0, oacc[mi], 0, 0, 0);
      bf16x8 q1 = *(const bf16x8*)&Qsm[mi * 16 + lm][lk8 + 32];
      oacc[mi] = __builtin_amdgcn_mfma_f32_16x16x32_bf16(q1, sfr1, oacc[mi], 0, 0, 0);
    }
#pragma unroll
    for (int mi = 0; mi < 4; ++mi) {
      bf16x8 a0 = *(const bf16x8*)&Amm[mi * 16 + lm][lk8];
      oacc[mi] = __builtin_amdgcn_mfma_f32_16x16x32_bf16(a0, dfr0, oacc[mi], 0, 0, 0);
      bf16x8 a1 = *(const bf16x8*)&Amm[mi * 16 + lm][lk8 + 32];
      oacc[mi] = __builtin_amdgcn_mfma_f32_16x16x32_bf16(a1, dfr1, oacc[mi], 0, 0, 0);
    }
#pragma unroll
    for (int mi = 0; mi < 4; ++mi)
#pragma unroll
      for (int r = 0; r < 4; ++r) {
        const int t = mi * 16 + r0 + r;
        o[(sb + t) * VALD_ + h * 64 + wv * 16 + cn] = oacc[mi][r];
      }
  }
}

// ---------------------------------------------------------------------------
// gnorm3 (r5-validated): h = o*silu(z); rmsnorm; *w -> bf16 hn. Vectorized.
// ---------------------------------------------------------------------------
__global__ __launch_bounds__(256) void gnorm3(const float* __restrict__ o,
                                              const float* __restrict__ z,
                                              const float* __restrict__ nw,
                                              bf16* __restrict__ hn) {
  const long idx = (long)blockIdx.x * 256 + threadIdx.x;  // M*16
  const float* op = o + idx * 64;
  const float* zp = z + idx * 64;
  float4 hv[16];
  float ss = 0.f;
#pragma unroll
  for (int i = 0; i < 16; ++i) {
    const float4 ov = *(const float4*)(op + i * 4);
    const float4 zv = *(const float4*)(zp + i * 4);
    float4 h;
    h.x = ov.x * (zv.x / (1.f + __expf(-zv.x)));
    h.y = ov.y * (zv.y / (1.f + __expf(-zv.y)));
    h.z = ov.z * (zv.z / (1.f + __expf(-zv.z)));
    h.w = ov.w * (zv.w / (1.f + __expf(-zv.w)));
    hv[i] = h;
    ss = fmaf(h.x, h.x, ss); ss = fmaf(h.y, h.y, ss);
    ss = fmaf(h.z, h.z, ss); ss = fmaf(h.w, h.w, ss);
  }
  const float r = rsqrtf(ss * (1.f / 64.f) + 1e-6f);
#pragma unroll
  for (int i = 0; i < 16; i += 2) {
    const float4 w0 = *(const float4*)(nw + i * 4);
    const float4 w1 = *(const float4*)(nw + i * 4 + 4);
    bf16x8 pk;
    pk[0] = f2bsh(hv[i].x * r * w0.x);     pk[1] = f2bsh(hv[i].y * r * w0.y);
    pk[2] = f2bsh(hv[i].z * r * w0.z);     pk[3] = f2bsh(hv[i].w * r * w0.w);
    pk[4] = f2bsh(hv[i + 1].x * r * w1.x); pk[5] = f2bsh(hv[i + 1].y * r * w1.y);
    pk[6] = f2bsh(hv[i + 1].z * r * w1.z); pk[7] = f2bsh(hv[i + 1].w * r * w1.w);
    *(bf16x8*)((uint16_t*)hn + idx * 64 + i * 4) = pk;
  }
}

// ---------------------------------------------------------------------------
extern "C" void kernel_launch(void* const* d_in, const int* in_sizes, int n_in,
                              void* d_out, int out_size, void* d_ws, size_t ws_size,
                              hipStream_t stream) {
  float* out = (float*)d_out;   // fp32 output (r8-confirmed)
  const int M = B_ * S_;        // 8192

  // input mapping (dict order confirmed; size-based fallback kept)
  int ih, iqkv, icw, iz, ib, ia, idtb, ialog, inw, iout;
  if (n_in >= 10 && in_sizes[0] == 8388608) {
    ih = 0; iqkv = 1; icw = 2; iz = 3; ib = 4; ia = 5;
    idtb = 6; ialog = 7; inw = 8; iout = 9;
  } else {
    ih = iqkv = icw = iz = ib = ia = idtb = ialog = inw = iout = -1;
    for (int i = 0; i < n_in; ++i) {
      switch (in_sizes[i]) {
        case 8388608: ih = i; break;
        case 2097152: iqkv = i; break;
        case 8192:    icw = i; break;
        case 64:      inw = i; break;
        case 1048576: if (iz < 0) iz = i; else iout = i; break;
        case 16384:   if (ib < 0) ib = i; else ia = i; break;
        case 16:      if (idtb < 0) idtb = i; else ialog = i; break;
        default: break;
      }
    }
  }
  const float* hs   = (const float*)d_in[ih];
  const float* Wqkv = (const float*)d_in[iqkv];
  const float* cw   = (const float*)d_in[icw];
  const float* Wz   = (const float*)d_in[iz];
  const float* Wb   = (const float*)d_in[ib];
  const float* Wa   = (const float*)d_in[ia];
  const float* dtb  = (const float*)d_in[idtb];
  const float* Alog = (const float*)d_in[ialog];
  const float* nwv  = (const float*)d_in[inw];
  const float* Wout = (const float*)d_in[iout];

  // workspace (~122 MiB): r2 layout; Mc/Bc alias region1 (mixed dead after
  // conv; of not written until chunk_out).
  char* p = (char*)d_ws;
  bf16*  mixed = (bf16*)p;                                 // region1: 32 MiB
  float* of    = (float*)p;                                //   of aliases mixed
  bf16*  McTw  = (bf16*)p;                                 //   McT: first 16 MiB
  bf16*  Bcw   = (bf16*)(p + (size_t)2048 * 4096 * 2);     //   Bc: second 16 MiB
  p += (size_t)M * CDIM_ * 2;
  bf16*  hs_b  = (bf16*)p;                                 // region2 (16 MiB; dead after z-gemm)
  bf16*  qkvb  = (bf16*)p;                                 //   full region2
  bf16*  hn    = (bf16*)p; p += (size_t)M * CDIM_ * 2;     //   hn aliases qkvb
  bf16*  Wqkv_b= (bf16*)p; p += (size_t)CDIM_ * H_ * 2;    // 4 MiB
  bf16*  Wz_b  = (bf16*)p; p += (size_t)H_ * H_ * 2;       // 2 MiB
  bf16*  Wout_b= (bf16*)p; p += (size_t)H_ * H_ * 2;       // 2 MiB
  float* betaf = (float*)p; p += (size_t)M * NVH_ * 4;     // 512 KiB
  float* gf    = (float*)p; p += (size_t)M * NVH_ * 4;     // 512 KiB
  bf16*  Wws   = (bf16*)p; p += (size_t)2048 * 4096 * 2;   // 16 MiB
  bf16*  U0ws  = (bf16*)p; p += (size_t)2048 * 4096 * 2;   // 16 MiB
  float* lgws  = (float*)p; p += (size_t)2048 * 64 * 4;    // 512 KiB
  bf16*  Sbw   = (bf16*)p; p += (size_t)2048 * 4096 * 2;   // 16 MiB (boundary states)
  float* zb    = out;   // z fp32 staged in d_out, consumed by gnorm3

  // 0) casts fp32 -> bf16 for MFMA operands
  {
    long n;
    n = (long)M * H_;     castf2b<<<(int)(n / 4 / 256), 256, 0, stream>>>(hs,   hs_b,   n);
    n = (long)CDIM_ * H_; castf2b<<<(int)(n / 4 / 256), 256, 0, stream>>>(Wqkv, Wqkv_b, n);
    n = (long)H_ * H_;    castf2b<<<(int)(n / 4 / 256), 256, 0, stream>>>(Wz,   Wz_b,   n);
    n = (long)H_ * H_;    castf2b<<<(int)(n / 4 / 256), 256, 0, stream>>>(Wout, Wout_b, n);
  }
  // 1) mixed = hs @ Wqkv^T  [8192 x 2048] -> bf16 (MFMA)
  gemm_bt<bf16><<<(M / 128) * (CDIM_ / 128), 256, 0, stream>>>(hs_b, Wqkv_b, mixed, M, CDIM_, H_);
  // 2) z = hs @ Wz^T  [8192 x 1024] -> fp32 in d_out (MFMA)
  gemm_bt<float><<<(M / 128) * (H_ / 128), 256, 0, stream>>>(hs_b, Wz_b, zb, M, H_, H_);
  // 3) beta, g (8 rows per block)
  proj_ba2<<<M / 8, 256, 0, stream>>>(hs, Wb, Wa, dtb, Alog, betaf, gf);
  // 4) causal depthwise conv + silu + q-scale -> bf16 (8 ch/thread vectorized)
  conv3<<<(int)(((long)M * CDIM_) / 8 / 256), 256, 0, stream>>>(mixed, cw, qkvb);
  // 5) chunked delta-rule, decoupled:
  //    a) UT-transform precompute + affine transition pieces (fused; 2048 WGs)
  chunk_pre<<<2048, 256, 0, stream>>>(qkvb, betaf, gf, Wws, U0ws, lgws, McTw, Bcw);
  //    b) serial boundary-state recurrence (32 WGs, 4 chunks/barrier-group)
  chunk_state<<<32, 256, 0, stream>>>(McTw, Bcw, lgws, Sbw);
  //    c) per-chunk outputs (parallel 2048)
  chunk_out<<<2048, 256, 0, stream>>>(qkvb, Wws, U0ws, lgws, Sbw, of);
  // 6) gated RMSNorm -> hn bf16 (vectorized)
  gnorm3<<<(M * NVH_) / 256, 256, 0, stream>>>(of, zb, nwv, hn);
  // 7) out = hn @ Wout^T -> d_out fp32 (MFMA)
  gemm_bt<float><<<(M / 128) * (H_ / 128), 256, 0, stream>>>(hn, Wout_b, out, M, H_, H_);
}